// Round 16
// baseline (73.254 us; speedup 1.0000x reference)
//
#include <hip/hip_runtime.h>
#include <hip/hip_bf16.h>
#include <cstddef>

typedef __attribute__((ext_vector_type(8))) short bf16x8;
typedef __attribute__((ext_vector_type(4))) float f32x4;

__device__ __forceinline__ float4 ld4(const float* p) { return *(const float4*)p; }
__device__ __forceinline__ unsigned short f2bf(float v) {
  __hip_bfloat16 h = __float2bfloat16(v);
  return *(unsigned short*)&h;
}

__device__ __forceinline__ bf16x8 pack8(float v0, float v1, float v2, float v3,
                                        float v4, float v5, float v6, float v7) {
  bf16x8 r;
  r[0] = (short)f2bf(v0); r[1] = (short)f2bf(v1);
  r[2] = (short)f2bf(v2); r[3] = (short)f2bf(v3);
  r[4] = (short)f2bf(v4); r[5] = (short)f2bf(v5);
  r[6] = (short)f2bf(v6); r[7] = (short)f2bf(v7);
  return r;
}
// 8 contiguous fp32 -> bf16x8 (A-fragments: weight rows)
__device__ __forceinline__ bf16x8 cfrag(const float* __restrict__ p) {
  float4 a = ld4(p), b = ld4(p + 4);
  return pack8(a.x, a.y, a.z, a.w, b.x, b.y, b.z, b.w);
}
// 8 strided fp32 -> bf16x8 (B-fragments: input channel walk at fixed pixel)
__device__ __forceinline__ bf16x8 gfrag(const float* __restrict__ p, int stride) {
  float v0 = p[0], v1 = p[stride], v2 = p[2 * stride], v3 = p[3 * stride];
  float v4 = p[4 * stride], v5 = p[5 * stride], v6 = p[6 * stride], v7 = p[7 * stride];
  return pack8(v0, v1, v2, v3, v4, v5, v6, v7);
}
__device__ __forceinline__ bf16x8 gfrag_guard(const float* __restrict__ p, int stride, bool ok) {
  float v0 = ok ? p[0] : 0.f, v1 = ok ? p[stride] : 0.f;
  float v2 = ok ? p[2 * stride] : 0.f, v3 = ok ? p[3 * stride] : 0.f;
  float v4 = ok ? p[4 * stride] : 0.f, v5 = ok ? p[5 * stride] : 0.f;
  float v6 = ok ? p[6 * stride] : 0.f, v7 = ok ? p[7 * stride] : 0.f;
  return pack8(v0, v1, v2, v3, v4, v5, v6, v7);
}

// 2x bilinear upsample of one 2x2 quad (three halo-resolved source rows).
__device__ __forceinline__ void up_quad_rows(const float* __restrict__ s0,
                                             const float* __restrict__ s1,
                                             const float* __restrict__ s2,
                                             int qx, int W, float* __restrict__ dst, int pitch) {
  int cm = qx > 0 ? qx - 1 : 0, cp = qx < W - 1 ? qx + 1 : W - 1;
  float tA0 = 0.25f * s0[cm] + 0.75f * s0[qx], tA1 = 0.75f * s0[qx] + 0.25f * s0[cp];
  float tB0 = 0.25f * s1[cm] + 0.75f * s1[qx], tB1 = 0.75f * s1[qx] + 0.25f * s1[cp];
  float tC0 = 0.25f * s2[cm] + 0.75f * s2[qx], tC1 = 0.75f * s2[qx] + 0.25f * s2[cp];
  *(float2*)dst = make_float2(0.25f * tA0 + 0.75f * tB0, 0.25f * tA1 + 0.75f * tB1);
  *(float2*)(dst + pitch) = make_float2(0.75f * tB0 + 0.25f * tC0, 0.75f * tB1 + 0.25f * tC1);
}

// 2x upsample of TWO adjacent quads (qx0 even): 4-wide x 2-row patch, float4 stores.
__device__ __forceinline__ void up_quad2(const float* __restrict__ s0,
                                         const float* __restrict__ s1,
                                         const float* __restrict__ s2,
                                         int qx0, int W, float* __restrict__ dst, int pitch) {
  int cm = qx0 > 0 ? qx0 - 1 : 0;
  int c2 = qx0 + 2 < W ? qx0 + 2 : W - 1;
  float Am = s0[cm], A0 = s0[qx0], A1 = s0[qx0 + 1], A2 = s0[c2];
  float Bm = s1[cm], B0 = s1[qx0], B1 = s1[qx0 + 1], B2 = s1[c2];
  float Cm = s2[cm], C0 = s2[qx0], C1 = s2[qx0 + 1], C2 = s2[c2];
  float hA0 = 0.25f * Am + 0.75f * A0, hA1 = 0.75f * A0 + 0.25f * A1;
  float hA2 = 0.25f * A0 + 0.75f * A1, hA3 = 0.75f * A1 + 0.25f * A2;
  float hB0 = 0.25f * Bm + 0.75f * B0, hB1 = 0.75f * B0 + 0.25f * B1;
  float hB2 = 0.25f * B0 + 0.75f * B1, hB3 = 0.75f * B1 + 0.25f * B2;
  float hC0 = 0.25f * Cm + 0.75f * C0, hC1 = 0.75f * C0 + 0.25f * C1;
  float hC2 = 0.25f * C0 + 0.75f * C1, hC3 = 0.75f * C1 + 0.25f * C2;
  *(float4*)dst = make_float4(0.25f * hA0 + 0.75f * hB0, 0.25f * hA1 + 0.75f * hB1,
                              0.25f * hA2 + 0.75f * hB2, 0.25f * hA3 + 0.75f * hB3);
  *(float4*)(dst + pitch) = make_float4(0.75f * hB0 + 0.25f * hC0, 0.75f * hB1 + 0.25f * hC1,
                                        0.75f * hB2 + 0.25f * hC2, 0.75f * hB3 + 0.25f * hC3);
}

struct P1M { float ct[16][252]; int inv[4][16]; };
struct C2M { float ct[32][126]; };
struct C3M { float ct[64][49]; };
union SmemM { P1M p1; C2M c2; C3M c3; };

// ---------------------------------------------------------------------------
// fused_all: ONE launch, 1984 blocks x 256 thr.
// SEGMENT-INTERLEAVED dispatch: per XCD, repeating 31-slot pattern
// {16 perm1, 8 conv2, 4 conv3, 2 conv4, 1 copies} so each CU hosts a MIX of
// block types (phase staggering: some blocks read while others write).
// Batch b -> XCD b&7 (panel L2 locality); all segments of b run in the same
// slot-epoch g = b>>3.
// decode: d -> xcd=d&7, slot=d>>3, g=slot/31, r=slot%31, b=g*8+xcd.
//   r in [0,16):  perm1, i=r      (o0=(i>>2)*16, r0=(i&3)*7)
//   r in [16,24): conv2, i=r-16   (o0=(i>>1)*32, r0=(i&1)*7)
//   r in [24,28): conv3, i=r-24   (o0=i*64)
//   r in [28,30): conv4, i=r-28   (ob=i*256+wave*64)
//   r == 30:      copies, cid=g*8+xcd (0..63)
// ---------------------------------------------------------------------------
__global__ void __launch_bounds__(256)
fused_all(const float* __restrict__ f1, const float* __restrict__ f2,
          const float* __restrict__ f3, const float* __restrict__ f4,
          const float* __restrict__ cw1, const float* __restrict__ cb1,
          const float* __restrict__ cw2, const float* __restrict__ cb2,
          const float* __restrict__ cw3, const float* __restrict__ cb3,
          const float* __restrict__ cw4, const float* __restrict__ cb4,
          const float* __restrict__ xf, const float* __restrict__ w1,
          const float* __restrict__ w2, const float* __restrict__ w3,
          const float* __restrict__ w4s, const int* __restrict__ perms,
          float* __restrict__ out) {
  __shared__ SmemM sm;
  const int d = blockIdx.x, tid = threadIdx.x;
  const int xcd = d & 7;
  const int slot = d >> 3;
  const int g = slot / 31;
  const int r = slot - g * 31;
  const int b = g * 8 + xcd;
  const int wave = tid >> 6, lane = tid & 63;
  const int l15 = lane & 15, lg = lane >> 4;
  float* o_aux1 = out + 32768;
  float* o_aux2 = o_aux1 + 12845056;
  float* o_aux3 = o_aux2 + 6422528;
  float* o_aux4 = o_aux3 + 3211264;

  if (r < 16) {
    // ================= perm1 (16 och x 7-row chunk) =================
    const int i = r;
    const int o0 = (i >> 2) * 16;
    const int r0 = (i & 3) * 7, base = r0 - 1;
    const float* f1b = f1 + (size_t)b * 50176;

    if (tid >= 128 && tid < 192) {
      int t2 = tid - 128;
      int qi = t2 >> 4, cl = t2 & 15;
      int c = o0 + cl;
      int rr = 0;
      for (int j = 0; j < 64; ++j)
        if (perms[qi * 64 + j] == c) rr = j;
      sm.p1.inv[qi][cl] = rr;
    }

    int off[4];
#pragma unroll
    for (int j = 0; j < 4; ++j) {
      int praw = wave * 64 + j * 16 + l15;
      int p = praw < 251 ? praw : 251;
      int lr = p / 28, x = p - lr * 28;
      int sr = base + lr;
      sr = sr < 0 ? 0 : (sr > 27 ? 27 : sr);
      off[j] = sr * 28 + x;
    }
    f32x4 acc[4];
    {
      float bv0 = cb1[o0 + lg * 4 + 0], bv1 = cb1[o0 + lg * 4 + 1];
      float bv2 = cb1[o0 + lg * 4 + 2], bv3 = cb1[o0 + lg * 4 + 3];
#pragma unroll
      for (int j = 0; j < 4; ++j) {
        acc[j][0] = bv0; acc[j][1] = bv1; acc[j][2] = bv2; acc[j][3] = bv3;
      }
    }
    const float* ap = cw1 + (size_t)(o0 + l15) * 64 + lg * 8;
#pragma unroll
    for (int ks = 0; ks < 2; ++ks) {
      bf16x8 A = cfrag(ap + ks * 32);
      const float* fb = f1b + (size_t)(ks * 32 + lg * 8) * 784;
#pragma unroll
      for (int j = 0; j < 4; ++j) {
        bf16x8 B = gfrag(fb + off[j], 784);
        acc[j] = __builtin_amdgcn_mfma_f32_16x16x32_bf16(A, B, acc[j], 0, 0, 0);
      }
    }
#pragma unroll
    for (int j = 0; j < 4; ++j) {
      int praw = wave * 64 + j * 16 + l15;
      if (praw < 252) {
#pragma unroll
        for (int rr = 0; rr < 4; ++rr) sm.p1.ct[lg * 4 + rr][praw] = acc[j][rr];
      }
    }
    __syncthreads();

    const size_t obase = (size_t)b * 200704;
    for (int i2 = tid; i2 < 1568; i2 += 256) {
      int cl = i2 / 98;
      int rem = i2 - cl * 98;
      int ly = rem / 14, pr = rem - ly * 14;
      int qx0 = 2 * pr;
      int qy = r0 + ly;
      int lr = ly + 1;
      int qi = ((qy >= 14) ? 2 : 0) + ((qx0 >= 14) ? 1 : 0);
      int j = sm.p1.inv[qi][cl];
      float* dst = o_aux1 + obase + (size_t)j * 3136 + (size_t)(2 * qy) * 56 + 2 * qx0;
      up_quad2(&sm.p1.ct[cl][(lr - 1) * 28], &sm.p1.ct[cl][lr * 28],
               &sm.p1.ct[cl][(lr + 1) * 28], qx0, 28, dst, 56);
    }
  } else if (r < 24) {
    // ================= conv2 (32 och x 7-row chunk) =================
    const int i = r - 16;
    const int o0 = (i >> 1) * 32;
    const int r0 = (i & 1) * 7, base = r0 - 1;
    const int og = wave >> 1, nt = wave & 1;
    const int om = o0 + og * 16;
    const float* f2b = f2 + (size_t)b * 25088;

    int off[4];
#pragma unroll
    for (int j = 0; j < 4; ++j) {
      int praw = nt * 64 + j * 16 + l15;
      int p = praw < 125 ? praw : 125;
      int lr = p / 14, x = p - lr * 14;
      int sr = base + lr;
      sr = sr < 0 ? 0 : (sr > 13 ? 13 : sr);
      off[j] = sr * 14 + x;
    }
    f32x4 acc[4];
    {
      float bv0 = cb2[om + lg * 4 + 0], bv1 = cb2[om + lg * 4 + 1];
      float bv2 = cb2[om + lg * 4 + 2], bv3 = cb2[om + lg * 4 + 3];
#pragma unroll
      for (int j = 0; j < 4; ++j) {
        acc[j][0] = bv0; acc[j][1] = bv1; acc[j][2] = bv2; acc[j][3] = bv3;
      }
    }
    const float* ap = cw2 + (size_t)(om + l15) * 128 + lg * 8;
#pragma unroll
    for (int ks = 0; ks < 4; ++ks) {
      bf16x8 A = cfrag(ap + ks * 32);
      const float* fb = f2b + (size_t)(ks * 32 + lg * 8) * 196;
#pragma unroll
      for (int j = 0; j < 4; ++j) {
        bf16x8 B = gfrag(fb + off[j], 196);
        acc[j] = __builtin_amdgcn_mfma_f32_16x16x32_bf16(A, B, acc[j], 0, 0, 0);
      }
    }
#pragma unroll
    for (int j = 0; j < 4; ++j) {
      int praw = nt * 64 + j * 16 + l15;
      if (praw < 126) {
#pragma unroll
        for (int rr = 0; rr < 4; ++rr) sm.c2.ct[og * 16 + lg * 4 + rr][praw] = acc[j][rr];
      }
    }
    __syncthreads();

    const size_t obase = (size_t)b * 100352;
    for (int i2 = tid; i2 < 1568; i2 += 256) {
      int cl = i2 / 49;
      int rem = i2 - cl * 49;
      int ly = rem / 7, pr = rem - ly * 7;
      int qx0 = 2 * pr;
      int qy = r0 + ly;
      int lr = ly + 1;
      float* dst = o_aux2 + obase + (size_t)(o0 + cl) * 784 + (size_t)(2 * qy) * 28 + 2 * qx0;
      up_quad2(&sm.c2.ct[cl][(lr - 1) * 14], &sm.c2.ct[cl][lr * 14],
               &sm.c2.ct[cl][(lr + 1) * 14], qx0, 14, dst, 28);
    }
  } else if (r < 28) {
    // ================= conv3 (64 och) =================
    const int i = r - 24;
    const int o0 = i * 64;
    const int om = o0 + wave * 16;
    const float* f3b = f3 + (size_t)b * 6272;

    int poff[4]; bool pok[4];
#pragma unroll
    for (int j = 0; j < 4; ++j) {
      int p = j * 16 + l15;
      pok[j] = p < 49;
      poff[j] = pok[j] ? p : 0;
    }
    f32x4 acc[4];
    {
      float bv0 = cb3[om + lg * 4 + 0], bv1 = cb3[om + lg * 4 + 1];
      float bv2 = cb3[om + lg * 4 + 2], bv3 = cb3[om + lg * 4 + 3];
#pragma unroll
      for (int j = 0; j < 4; ++j) {
        acc[j][0] = bv0; acc[j][1] = bv1; acc[j][2] = bv2; acc[j][3] = bv3;
      }
    }
    const float* ap = cw3 + (size_t)(om + l15) * 128 + lg * 8;
#pragma unroll
    for (int ks = 0; ks < 4; ++ks) {
      bf16x8 A = cfrag(ap + ks * 32);
      const float* fb = f3b + (size_t)(ks * 32 + lg * 8) * 49;
#pragma unroll
      for (int j = 0; j < 4; ++j) {
        bf16x8 B = gfrag_guard(fb + poff[j], 49, pok[j]);
        acc[j] = __builtin_amdgcn_mfma_f32_16x16x32_bf16(A, B, acc[j], 0, 0, 0);
      }
    }
#pragma unroll
    for (int j = 0; j < 4; ++j) {
      int p = j * 16 + l15;
      if (p < 49) {
#pragma unroll
        for (int rr = 0; rr < 4; ++rr) sm.c3.ct[wave * 16 + lg * 4 + rr][p] = acc[j][rr];
      }
    }
    __syncthreads();

    const size_t obase = (size_t)b * 50176;
    for (int i2 = tid; i2 < 64 * 49; i2 += 256) {
      int cl = i2 / 49;
      int q = i2 - cl * 49;
      int qy = q / 7, qx = q - qy * 7;
      int rm = qy > 0 ? qy - 1 : 0, rp = qy < 6 ? qy + 1 : 6;
      float* dst = o_aux3 + obase + (size_t)(o0 + cl) * 196 + (size_t)(2 * qy) * 14 + 2 * qx;
      up_quad_rows(&sm.c3.ct[cl][rm * 7], &sm.c3.ct[cl][qy * 7], &sm.c3.ct[cl][rp * 7],
                   qx, 7, dst, 14);
    }
  } else if (r < 30) {
    // ================= conv4 (wave = 64 och, B built once; M=4) ============
    const int i = r - 28;
    const int ob = i * 256 + wave * 64;
    const float* f4b = f4 + (size_t)b * 25088;

    f32x4 acc[4][4];
#pragma unroll
    for (int mi = 0; mi < 4; ++mi) {
      float bv0 = cb4[ob + mi * 16 + lg * 4 + 0], bv1 = cb4[ob + mi * 16 + lg * 4 + 1];
      float bv2 = cb4[ob + mi * 16 + lg * 4 + 2], bv3 = cb4[ob + mi * 16 + lg * 4 + 3];
#pragma unroll
      for (int n = 0; n < 4; ++n) {
        acc[mi][n][0] = bv0; acc[mi][n][1] = bv1; acc[mi][n][2] = bv2; acc[mi][n][3] = bv3;
      }
    }
    int poff[4]; bool pok[4];
#pragma unroll
    for (int n = 0; n < 4; ++n) {
      int p = n * 16 + l15;
      pok[n] = p < 49;
      poff[n] = pok[n] ? p : 0;
    }
#pragma unroll 1
    for (int k0 = 0; k0 < 512; k0 += 32) {
      bf16x8 A0 = cfrag(cw4 + (size_t)(ob + 0 + l15) * 512 + k0 + lg * 8);
      bf16x8 A1 = cfrag(cw4 + (size_t)(ob + 16 + l15) * 512 + k0 + lg * 8);
      bf16x8 A2 = cfrag(cw4 + (size_t)(ob + 32 + l15) * 512 + k0 + lg * 8);
      bf16x8 A3 = cfrag(cw4 + (size_t)(ob + 48 + l15) * 512 + k0 + lg * 8);
      const float* fb = f4b + (size_t)(k0 + lg * 8) * 49;
      bf16x8 B0 = gfrag_guard(fb + poff[0], 49, pok[0]);
      bf16x8 B1 = gfrag_guard(fb + poff[1], 49, pok[1]);
      bf16x8 B2 = gfrag_guard(fb + poff[2], 49, pok[2]);
      bf16x8 B3 = gfrag_guard(fb + poff[3], 49, pok[3]);
      acc[0][0] = __builtin_amdgcn_mfma_f32_16x16x32_bf16(A0, B0, acc[0][0], 0, 0, 0);
      acc[0][1] = __builtin_amdgcn_mfma_f32_16x16x32_bf16(A0, B1, acc[0][1], 0, 0, 0);
      acc[0][2] = __builtin_amdgcn_mfma_f32_16x16x32_bf16(A0, B2, acc[0][2], 0, 0, 0);
      acc[0][3] = __builtin_amdgcn_mfma_f32_16x16x32_bf16(A0, B3, acc[0][3], 0, 0, 0);
      acc[1][0] = __builtin_amdgcn_mfma_f32_16x16x32_bf16(A1, B0, acc[1][0], 0, 0, 0);
      acc[1][1] = __builtin_amdgcn_mfma_f32_16x16x32_bf16(A1, B1, acc[1][1], 0, 0, 0);
      acc[1][2] = __builtin_amdgcn_mfma_f32_16x16x32_bf16(A1, B2, acc[1][2], 0, 0, 0);
      acc[1][3] = __builtin_amdgcn_mfma_f32_16x16x32_bf16(A1, B3, acc[1][3], 0, 0, 0);
      acc[2][0] = __builtin_amdgcn_mfma_f32_16x16x32_bf16(A2, B0, acc[2][0], 0, 0, 0);
      acc[2][1] = __builtin_amdgcn_mfma_f32_16x16x32_bf16(A2, B1, acc[2][1], 0, 0, 0);
      acc[2][2] = __builtin_amdgcn_mfma_f32_16x16x32_bf16(A2, B2, acc[2][2], 0, 0, 0);
      acc[2][3] = __builtin_amdgcn_mfma_f32_16x16x32_bf16(A2, B3, acc[2][3], 0, 0, 0);
      acc[3][0] = __builtin_amdgcn_mfma_f32_16x16x32_bf16(A3, B0, acc[3][0], 0, 0, 0);
      acc[3][1] = __builtin_amdgcn_mfma_f32_16x16x32_bf16(A3, B1, acc[3][1], 0, 0, 0);
      acc[3][2] = __builtin_amdgcn_mfma_f32_16x16x32_bf16(A3, B2, acc[3][2], 0, 0, 0);
      acc[3][3] = __builtin_amdgcn_mfma_f32_16x16x32_bf16(A3, B3, acc[3][3], 0, 0, 0);
    }
    float* outb = o_aux4 + (size_t)b * 25088;
#pragma unroll
    for (int mi = 0; mi < 4; ++mi) {
#pragma unroll
      for (int n = 0; n < 4; ++n) {
        int p = n * 16 + l15;
        if (p < 49) {
#pragma unroll
          for (int rr = 0; rr < 4; ++rr) {
            int o = ob + mi * 16 + lg * 4 + rr;
            outb[(size_t)o * 49 + p] = acc[mi][n][rr];
          }
        }
      }
    }
  } else {
    // ================= copies (64 logical blocks) =================
    const int cid = g * 8 + xcd;  // 0..63
    int idx = cid * 256 + tid;
    const int stride = 64 * 256;
    float4* o4 = (float4*)out;
    const size_t W1 = 6029312;  // o_w1 offset in float4s
    for (int i2 = idx; i2 < 8192; i2 += stride) o4[i2] = ((const float4*)xf)[i2];
    for (int i2 = idx; i2 < 50176; i2 += stride) o4[W1 + i2] = ((const float4*)w1)[i2];
    for (int i2 = idx; i2 < 25088; i2 += stride) o4[W1 + 50176 + i2] = ((const float4*)w2)[i2];
    for (int i2 = idx; i2 < 12544; i2 += stride) o4[W1 + 75264 + i2] = ((const float4*)w3)[i2];
    for (int i2 = idx; i2 < 6272; i2 += stride) o4[W1 + 87808 + i2] = ((const float4*)w4s)[i2];
  }
}

extern "C" void kernel_launch(void* const* d_in, const int* in_sizes, int n_in,
                              void* d_out, int out_size, void* d_ws, size_t ws_size,
                              hipStream_t stream) {
  const float* f1      = (const float*)d_in[0];
  const float* f2      = (const float*)d_in[1];
  const float* f3      = (const float*)d_in[2];
  const float* f4      = (const float*)d_in[3];
  const float* x_final = (const float*)d_in[4];
  const float* cw1     = (const float*)d_in[5];
  const float* cb1     = (const float*)d_in[6];
  const float* cw2     = (const float*)d_in[7];
  const float* cb2     = (const float*)d_in[8];
  const float* cw3     = (const float*)d_in[9];
  const float* cb3     = (const float*)d_in[10];
  const float* cw4     = (const float*)d_in[11];
  const float* cb4     = (const float*)d_in[12];
  const float* w1      = (const float*)d_in[13];
  const float* w2      = (const float*)d_in[14];
  const float* w3      = (const float*)d_in[15];
  const float* w4      = (const float*)d_in[16];
  const int*   perms   = (const int*)d_in[17];

  float* out = (float*)d_out;

  fused_all<<<1984, 256, 0, stream>>>(f1, f2, f3, f4, cw1, cb1, cw2, cb2,
                                      cw3, cb3, cw4, cb4, x_final, w1, w2, w3, w4,
                                      perms, out);
}

// Round 18
// 60.184 us; speedup vs baseline: 1.2172x; 1.2172x over previous
//
#include <hip/hip_runtime.h>
#include <hip/hip_bf16.h>
#include <cstddef>

typedef __attribute__((ext_vector_type(8))) short bf16x8;
typedef __attribute__((ext_vector_type(4))) float f32x4;
typedef __attribute__((ext_vector_type(2))) float f32x2;

__device__ __forceinline__ float4 ld4(const float* p) { return *(const float4*)p; }
__device__ __forceinline__ unsigned short f2bf(float v) {
  __hip_bfloat16 h = __float2bfloat16(v);
  return *(unsigned short*)&h;
}
// Nontemporal output stores (outputs never re-read; keep them out of L2).
// NOTE: __builtin_nontemporal_store requires clang ext_vector types, not
// HIP_vector_type structs (R17 compile failure).
__device__ __forceinline__ void st_nt4(float* p, float a, float b, float c, float d) {
  f32x4 t; t[0] = a; t[1] = b; t[2] = c; t[3] = d;
  __builtin_nontemporal_store(t, (f32x4*)p);
}
__device__ __forceinline__ void st_nt2(float* p, float a, float b) {
  f32x2 t; t[0] = a; t[1] = b;
  __builtin_nontemporal_store(t, (f32x2*)p);
}
__device__ __forceinline__ void st_nt1(float* p, float v) {
  __builtin_nontemporal_store(v, p);
}
__device__ __forceinline__ void st_nt4v(float* p, float4 v) {
  st_nt4(p, v.x, v.y, v.z, v.w);
}

__device__ __forceinline__ bf16x8 pack8(float v0, float v1, float v2, float v3,
                                        float v4, float v5, float v6, float v7) {
  bf16x8 r;
  r[0] = (short)f2bf(v0); r[1] = (short)f2bf(v1);
  r[2] = (short)f2bf(v2); r[3] = (short)f2bf(v3);
  r[4] = (short)f2bf(v4); r[5] = (short)f2bf(v5);
  r[6] = (short)f2bf(v6); r[7] = (short)f2bf(v7);
  return r;
}
// 8 contiguous fp32 -> bf16x8 (A-fragments: weight rows)
__device__ __forceinline__ bf16x8 cfrag(const float* __restrict__ p) {
  float4 a = ld4(p), b = ld4(p + 4);
  return pack8(a.x, a.y, a.z, a.w, b.x, b.y, b.z, b.w);
}
// 8 strided fp32 -> bf16x8 (B-fragments: input channel walk at fixed pixel)
__device__ __forceinline__ bf16x8 gfrag(const float* __restrict__ p, int stride) {
  float v0 = p[0], v1 = p[stride], v2 = p[2 * stride], v3 = p[3 * stride];
  float v4 = p[4 * stride], v5 = p[5 * stride], v6 = p[6 * stride], v7 = p[7 * stride];
  return pack8(v0, v1, v2, v3, v4, v5, v6, v7);
}
__device__ __forceinline__ bf16x8 gfrag_guard(const float* __restrict__ p, int stride, bool ok) {
  float v0 = ok ? p[0] : 0.f, v1 = ok ? p[stride] : 0.f;
  float v2 = ok ? p[2 * stride] : 0.f, v3 = ok ? p[3 * stride] : 0.f;
  float v4 = ok ? p[4 * stride] : 0.f, v5 = ok ? p[5 * stride] : 0.f;
  float v6 = ok ? p[6 * stride] : 0.f, v7 = ok ? p[7 * stride] : 0.f;
  return pack8(v0, v1, v2, v3, v4, v5, v6, v7);
}

// 2x bilinear upsample of one 2x2 quad (three halo-resolved source rows).
__device__ __forceinline__ void up_quad_rows(const float* __restrict__ s0,
                                             const float* __restrict__ s1,
                                             const float* __restrict__ s2,
                                             int qx, int W, float* __restrict__ dst, int pitch) {
  int cm = qx > 0 ? qx - 1 : 0, cp = qx < W - 1 ? qx + 1 : W - 1;
  float tA0 = 0.25f * s0[cm] + 0.75f * s0[qx], tA1 = 0.75f * s0[qx] + 0.25f * s0[cp];
  float tB0 = 0.25f * s1[cm] + 0.75f * s1[qx], tB1 = 0.75f * s1[qx] + 0.25f * s1[cp];
  float tC0 = 0.25f * s2[cm] + 0.75f * s2[qx], tC1 = 0.75f * s2[qx] + 0.25f * s2[cp];
  st_nt2(dst, 0.25f * tA0 + 0.75f * tB0, 0.25f * tA1 + 0.75f * tB1);
  st_nt2(dst + pitch, 0.75f * tB0 + 0.25f * tC0, 0.75f * tB1 + 0.25f * tC1);
}

// 2x upsample of TWO adjacent quads (qx0 even): 4-wide x 2-row patch, float4 stores.
__device__ __forceinline__ void up_quad2(const float* __restrict__ s0,
                                         const float* __restrict__ s1,
                                         const float* __restrict__ s2,
                                         int qx0, int W, float* __restrict__ dst, int pitch) {
  int cm = qx0 > 0 ? qx0 - 1 : 0;
  int c2 = qx0 + 2 < W ? qx0 + 2 : W - 1;
  float Am = s0[cm], A0 = s0[qx0], A1 = s0[qx0 + 1], A2 = s0[c2];
  float Bm = s1[cm], B0 = s1[qx0], B1 = s1[qx0 + 1], B2 = s1[c2];
  float Cm = s2[cm], C0 = s2[qx0], C1 = s2[qx0 + 1], C2 = s2[c2];
  float hA0 = 0.25f * Am + 0.75f * A0, hA1 = 0.75f * A0 + 0.25f * A1;
  float hA2 = 0.25f * A0 + 0.75f * A1, hA3 = 0.75f * A1 + 0.25f * A2;
  float hB0 = 0.25f * Bm + 0.75f * B0, hB1 = 0.75f * B0 + 0.25f * B1;
  float hB2 = 0.25f * B0 + 0.75f * B1, hB3 = 0.75f * B1 + 0.25f * B2;
  float hC0 = 0.25f * Cm + 0.75f * C0, hC1 = 0.75f * C0 + 0.25f * C1;
  float hC2 = 0.25f * C0 + 0.75f * C1, hC3 = 0.75f * C1 + 0.25f * C2;
  st_nt4(dst, 0.25f * hA0 + 0.75f * hB0, 0.25f * hA1 + 0.75f * hB1,
         0.25f * hA2 + 0.75f * hB2, 0.25f * hA3 + 0.75f * hB3);
  st_nt4(dst + pitch, 0.75f * hB0 + 0.25f * hC0, 0.75f * hB1 + 0.25f * hC1,
         0.75f * hB2 + 0.25f * hC2, 0.75f * hB3 + 0.25f * hC3);
}

struct P1M { float ct[16][252]; int inv[4][16]; };
struct C2M { float ct[32][126]; };
struct C3M { float ct[64][49]; };
union SmemM { P1M p1; C2M c2; C3M c3; };

// Balanced XCD-local decode: b gets XCD b%8; all wpb works of a batch share
// one XCD (panel L2 reuse); every XCD gets an equal share of every segment.
__device__ __forceinline__ int2 xcd_decode(int d, int wpb_log) {
  int xcd = d & 7;
  int i = (d >> 3) & ((1 << wpb_log) - 1);
  int b = (((d >> (3 + wpb_log)) << 3) | xcd);
  return make_int2(b, i);
}

// ---------------------------------------------------------------------------
// fused_all: ONE launch, 1984 blocks x 256 thr (R15 structure + nt-stores).
//  [0,128)     conv4: wave=64 och (M=4, B-dedup), 2 m-halves/batch
//  [128,1152)  perm1: 16 och x 7-row chunk
//  [1152,1664) conv2: 32 och x 7-row chunk
//  [1664,1920) conv3: 64 och
//  [1920,1984) copies
// ---------------------------------------------------------------------------
__global__ void __launch_bounds__(256)
fused_all(const float* __restrict__ f1, const float* __restrict__ f2,
          const float* __restrict__ f3, const float* __restrict__ f4,
          const float* __restrict__ cw1, const float* __restrict__ cb1,
          const float* __restrict__ cw2, const float* __restrict__ cb2,
          const float* __restrict__ cw3, const float* __restrict__ cb3,
          const float* __restrict__ cw4, const float* __restrict__ cb4,
          const float* __restrict__ xf, const float* __restrict__ w1,
          const float* __restrict__ w2, const float* __restrict__ w3,
          const float* __restrict__ w4s, const int* __restrict__ perms,
          float* __restrict__ out) {
  __shared__ SmemM sm;
  const int raw = blockIdx.x, tid = threadIdx.x;
  const int wave = tid >> 6, lane = tid & 63;
  const int l15 = lane & 15, lg = lane >> 4;
  float* o_aux1 = out + 32768;
  float* o_aux2 = o_aux1 + 12845056;
  float* o_aux3 = o_aux2 + 6422528;
  float* o_aux4 = o_aux3 + 3211264;

  if (raw < 128) {
    // ================= conv4 (wave = 64 och, B built once) =================
    int2 bi = xcd_decode(raw, 1);
    const int b = bi.x;
    const int ob = bi.y * 256 + wave * 64;
    const float* f4b = f4 + (size_t)b * 25088;

    f32x4 acc[4][4];
#pragma unroll
    for (int mi = 0; mi < 4; ++mi) {
      float bv0 = cb4[ob + mi * 16 + lg * 4 + 0], bv1 = cb4[ob + mi * 16 + lg * 4 + 1];
      float bv2 = cb4[ob + mi * 16 + lg * 4 + 2], bv3 = cb4[ob + mi * 16 + lg * 4 + 3];
#pragma unroll
      for (int n = 0; n < 4; ++n) {
        acc[mi][n][0] = bv0; acc[mi][n][1] = bv1; acc[mi][n][2] = bv2; acc[mi][n][3] = bv3;
      }
    }
    int poff[4]; bool pok[4];
#pragma unroll
    for (int n = 0; n < 4; ++n) {
      int p = n * 16 + l15;
      pok[n] = p < 49;
      poff[n] = pok[n] ? p : 0;
    }
#pragma unroll 1
    for (int k0 = 0; k0 < 512; k0 += 32) {
      bf16x8 A0 = cfrag(cw4 + (size_t)(ob + 0 + l15) * 512 + k0 + lg * 8);
      bf16x8 A1 = cfrag(cw4 + (size_t)(ob + 16 + l15) * 512 + k0 + lg * 8);
      bf16x8 A2 = cfrag(cw4 + (size_t)(ob + 32 + l15) * 512 + k0 + lg * 8);
      bf16x8 A3 = cfrag(cw4 + (size_t)(ob + 48 + l15) * 512 + k0 + lg * 8);
      const float* fb = f4b + (size_t)(k0 + lg * 8) * 49;
      bf16x8 B0 = gfrag_guard(fb + poff[0], 49, pok[0]);
      bf16x8 B1 = gfrag_guard(fb + poff[1], 49, pok[1]);
      bf16x8 B2 = gfrag_guard(fb + poff[2], 49, pok[2]);
      bf16x8 B3 = gfrag_guard(fb + poff[3], 49, pok[3]);
      acc[0][0] = __builtin_amdgcn_mfma_f32_16x16x32_bf16(A0, B0, acc[0][0], 0, 0, 0);
      acc[0][1] = __builtin_amdgcn_mfma_f32_16x16x32_bf16(A0, B1, acc[0][1], 0, 0, 0);
      acc[0][2] = __builtin_amdgcn_mfma_f32_16x16x32_bf16(A0, B2, acc[0][2], 0, 0, 0);
      acc[0][3] = __builtin_amdgcn_mfma_f32_16x16x32_bf16(A0, B3, acc[0][3], 0, 0, 0);
      acc[1][0] = __builtin_amdgcn_mfma_f32_16x16x32_bf16(A1, B0, acc[1][0], 0, 0, 0);
      acc[1][1] = __builtin_amdgcn_mfma_f32_16x16x32_bf16(A1, B1, acc[1][1], 0, 0, 0);
      acc[1][2] = __builtin_amdgcn_mfma_f32_16x16x32_bf16(A1, B2, acc[1][2], 0, 0, 0);
      acc[1][3] = __builtin_amdgcn_mfma_f32_16x16x32_bf16(A1, B3, acc[1][3], 0, 0, 0);
      acc[2][0] = __builtin_amdgcn_mfma_f32_16x16x32_bf16(A2, B0, acc[2][0], 0, 0, 0);
      acc[2][1] = __builtin_amdgcn_mfma_f32_16x16x32_bf16(A2, B1, acc[2][1], 0, 0, 0);
      acc[2][2] = __builtin_amdgcn_mfma_f32_16x16x32_bf16(A2, B2, acc[2][2], 0, 0, 0);
      acc[2][3] = __builtin_amdgcn_mfma_f32_16x16x32_bf16(A2, B3, acc[2][3], 0, 0, 0);
      acc[3][0] = __builtin_amdgcn_mfma_f32_16x16x32_bf16(A3, B0, acc[3][0], 0, 0, 0);
      acc[3][1] = __builtin_amdgcn_mfma_f32_16x16x32_bf16(A3, B1, acc[3][1], 0, 0, 0);
      acc[3][2] = __builtin_amdgcn_mfma_f32_16x16x32_bf16(A3, B2, acc[3][2], 0, 0, 0);
      acc[3][3] = __builtin_amdgcn_mfma_f32_16x16x32_bf16(A3, B3, acc[3][3], 0, 0, 0);
    }
    float* outb = o_aux4 + (size_t)b * 25088;
#pragma unroll
    for (int mi = 0; mi < 4; ++mi) {
#pragma unroll
      for (int n = 0; n < 4; ++n) {
        int p = n * 16 + l15;
        if (p < 49) {
#pragma unroll
          for (int r = 0; r < 4; ++r) {
            int o = ob + mi * 16 + lg * 4 + r;
            st_nt1(&outb[(size_t)o * 49 + p], acc[mi][n][r]);
          }
        }
      }
    }
  } else if (raw < 1152) {
    // ================= perm1 (16 och, 7-row chunk) =========================
    int2 bi = xcd_decode(raw - 128, 4);
    const int b = bi.x;
    const int o0 = (bi.y >> 2) * 16;
    const int r0 = (bi.y & 3) * 7, base = r0 - 1;
    const float* f1b = f1 + (size_t)b * 50176;

    if (tid >= 128 && tid < 192) {
      int t2 = tid - 128;
      int i = t2 >> 4, cl = t2 & 15;
      int c = o0 + cl;
      int r = 0;
      for (int j = 0; j < 64; ++j)
        if (perms[i * 64 + j] == c) r = j;
      sm.p1.inv[i][cl] = r;
    }

    int off[4];
#pragma unroll
    for (int j = 0; j < 4; ++j) {
      int praw = wave * 64 + j * 16 + l15;
      int p = praw < 251 ? praw : 251;
      int lr = p / 28, x = p - lr * 28;
      int sr = base + lr;
      sr = sr < 0 ? 0 : (sr > 27 ? 27 : sr);
      off[j] = sr * 28 + x;
    }
    f32x4 acc[4];
    {
      float bv0 = cb1[o0 + lg * 4 + 0], bv1 = cb1[o0 + lg * 4 + 1];
      float bv2 = cb1[o0 + lg * 4 + 2], bv3 = cb1[o0 + lg * 4 + 3];
#pragma unroll
      for (int j = 0; j < 4; ++j) {
        acc[j][0] = bv0; acc[j][1] = bv1; acc[j][2] = bv2; acc[j][3] = bv3;
      }
    }
    const float* ap = cw1 + (size_t)(o0 + l15) * 64 + lg * 8;
#pragma unroll
    for (int ks = 0; ks < 2; ++ks) {
      bf16x8 A = cfrag(ap + ks * 32);
      const float* fb = f1b + (size_t)(ks * 32 + lg * 8) * 784;
#pragma unroll
      for (int j = 0; j < 4; ++j) {
        bf16x8 B = gfrag(fb + off[j], 784);
        acc[j] = __builtin_amdgcn_mfma_f32_16x16x32_bf16(A, B, acc[j], 0, 0, 0);
      }
    }
#pragma unroll
    for (int j = 0; j < 4; ++j) {
      int praw = wave * 64 + j * 16 + l15;
      if (praw < 252) {
#pragma unroll
        for (int r = 0; r < 4; ++r) sm.p1.ct[lg * 4 + r][praw] = acc[j][r];
      }
    }
    __syncthreads();

    const size_t obase = (size_t)b * 200704;
    for (int i = tid; i < 1568; i += 256) {
      int cl = i / 98;
      int rem = i - cl * 98;
      int ly = rem / 14, pr = rem - ly * 14;
      int qx0 = 2 * pr;
      int qy = r0 + ly;
      int lr = ly + 1;
      int qi = ((qy >= 14) ? 2 : 0) + ((qx0 >= 14) ? 1 : 0);
      int j = sm.p1.inv[qi][cl];
      float* dst = o_aux1 + obase + (size_t)j * 3136 + (size_t)(2 * qy) * 56 + 2 * qx0;
      up_quad2(&sm.p1.ct[cl][(lr - 1) * 28], &sm.p1.ct[cl][lr * 28],
               &sm.p1.ct[cl][(lr + 1) * 28], qx0, 28, dst, 56);
    }
  } else if (raw < 1664) {
    // ================= conv2 (32 och, 7-row chunk) =========================
    int2 bi = xcd_decode(raw - 1152, 3);
    const int b = bi.x;
    const int o0 = (bi.y >> 1) * 32;
    const int r0 = (bi.y & 1) * 7, base = r0 - 1;
    const int og = wave >> 1, nt = wave & 1;
    const int om = o0 + og * 16;
    const float* f2b = f2 + (size_t)b * 25088;

    int off[4];
#pragma unroll
    for (int j = 0; j < 4; ++j) {
      int praw = nt * 64 + j * 16 + l15;
      int p = praw < 125 ? praw : 125;
      int lr = p / 14, x = p - lr * 14;
      int sr = base + lr;
      sr = sr < 0 ? 0 : (sr > 13 ? 13 : sr);
      off[j] = sr * 14 + x;
    }
    f32x4 acc[4];
    {
      float bv0 = cb2[om + lg * 4 + 0], bv1 = cb2[om + lg * 4 + 1];
      float bv2 = cb2[om + lg * 4 + 2], bv3 = cb2[om + lg * 4 + 3];
#pragma unroll
      for (int j = 0; j < 4; ++j) {
        acc[j][0] = bv0; acc[j][1] = bv1; acc[j][2] = bv2; acc[j][3] = bv3;
      }
    }
    const float* ap = cw2 + (size_t)(om + l15) * 128 + lg * 8;
#pragma unroll
    for (int ks = 0; ks < 4; ++ks) {
      bf16x8 A = cfrag(ap + ks * 32);
      const float* fb = f2b + (size_t)(ks * 32 + lg * 8) * 196;
#pragma unroll
      for (int j = 0; j < 4; ++j) {
        bf16x8 B = gfrag(fb + off[j], 196);
        acc[j] = __builtin_amdgcn_mfma_f32_16x16x32_bf16(A, B, acc[j], 0, 0, 0);
      }
    }
#pragma unroll
    for (int j = 0; j < 4; ++j) {
      int praw = nt * 64 + j * 16 + l15;
      if (praw < 126) {
#pragma unroll
        for (int r = 0; r < 4; ++r) sm.c2.ct[og * 16 + lg * 4 + r][praw] = acc[j][r];
      }
    }
    __syncthreads();

    const size_t obase = (size_t)b * 100352;
    for (int i = tid; i < 1568; i += 256) {
      int cl = i / 49;
      int rem = i - cl * 49;
      int ly = rem / 7, pr = rem - ly * 7;
      int qx0 = 2 * pr;
      int qy = r0 + ly;
      int lr = ly + 1;
      float* dst = o_aux2 + obase + (size_t)(o0 + cl) * 784 + (size_t)(2 * qy) * 28 + 2 * qx0;
      up_quad2(&sm.c2.ct[cl][(lr - 1) * 14], &sm.c2.ct[cl][lr * 14],
               &sm.c2.ct[cl][(lr + 1) * 14], qx0, 14, dst, 28);
    }
  } else if (raw < 1920) {
    // ================= conv3 (64 och) ======================================
    int2 bi = xcd_decode(raw - 1664, 2);
    const int b = bi.x;
    const int o0 = bi.y * 64;
    const int om = o0 + wave * 16;
    const float* f3b = f3 + (size_t)b * 6272;

    int poff[4]; bool pok[4];
#pragma unroll
    for (int j = 0; j < 4; ++j) {
      int p = j * 16 + l15;
      pok[j] = p < 49;
      poff[j] = pok[j] ? p : 0;
    }
    f32x4 acc[4];
    {
      float bv0 = cb3[om + lg * 4 + 0], bv1 = cb3[om + lg * 4 + 1];
      float bv2 = cb3[om + lg * 4 + 2], bv3 = cb3[om + lg * 4 + 3];
#pragma unroll
      for (int j = 0; j < 4; ++j) {
        acc[j][0] = bv0; acc[j][1] = bv1; acc[j][2] = bv2; acc[j][3] = bv3;
      }
    }
    const float* ap = cw3 + (size_t)(om + l15) * 128 + lg * 8;
#pragma unroll
    for (int ks = 0; ks < 4; ++ks) {
      bf16x8 A = cfrag(ap + ks * 32);
      const float* fb = f3b + (size_t)(ks * 32 + lg * 8) * 49;
#pragma unroll
      for (int j = 0; j < 4; ++j) {
        bf16x8 B = gfrag_guard(fb + poff[j], 49, pok[j]);
        acc[j] = __builtin_amdgcn_mfma_f32_16x16x32_bf16(A, B, acc[j], 0, 0, 0);
      }
    }
#pragma unroll
    for (int j = 0; j < 4; ++j) {
      int p = j * 16 + l15;
      if (p < 49) {
#pragma unroll
        for (int r = 0; r < 4; ++r) sm.c3.ct[wave * 16 + lg * 4 + r][p] = acc[j][r];
      }
    }
    __syncthreads();

    const size_t obase = (size_t)b * 50176;
    for (int i = tid; i < 64 * 49; i += 256) {
      int cl = i / 49;
      int q = i - cl * 49;
      int qy = q / 7, qx = q - qy * 7;
      int rm = qy > 0 ? qy - 1 : 0, rp = qy < 6 ? qy + 1 : 6;
      float* dst = o_aux3 + obase + (size_t)(o0 + cl) * 196 + (size_t)(2 * qy) * 14 + 2 * qx;
      up_quad_rows(&sm.c3.ct[cl][rm * 7], &sm.c3.ct[cl][qy * 7], &sm.c3.ct[cl][rp * 7],
                   qx, 7, dst, 14);
    }
  } else {
    // ================= copies =================
    int idx = (raw - 1920) * 256 + tid;
    const int stride = 64 * 256;
    float* of = out;
    const size_t W1f = 24117248;  // o_w1 offset in floats
    for (int i = idx; i < 8192; i += stride) st_nt4v(&of[4 * i], ((const float4*)xf)[i]);
    for (int i = idx; i < 50176; i += stride) st_nt4v(&of[W1f + 4 * i], ((const float4*)w1)[i]);
    for (int i = idx; i < 25088; i += stride) st_nt4v(&of[W1f + 200704 + 4 * i], ((const float4*)w2)[i]);
    for (int i = idx; i < 12544; i += stride) st_nt4v(&of[W1f + 301056 + 4 * i], ((const float4*)w3)[i]);
    for (int i = idx; i < 6272; i += stride) st_nt4v(&of[W1f + 351232 + 4 * i], ((const float4*)w4s)[i]);
  }
}

extern "C" void kernel_launch(void* const* d_in, const int* in_sizes, int n_in,
                              void* d_out, int out_size, void* d_ws, size_t ws_size,
                              hipStream_t stream) {
  const float* f1      = (const float*)d_in[0];
  const float* f2      = (const float*)d_in[1];
  const float* f3      = (const float*)d_in[2];
  const float* f4      = (const float*)d_in[3];
  const float* x_final = (const float*)d_in[4];
  const float* cw1     = (const float*)d_in[5];
  const float* cb1     = (const float*)d_in[6];
  const float* cw2     = (const float*)d_in[7];
  const float* cb2     = (const float*)d_in[8];
  const float* cw3     = (const float*)d_in[9];
  const float* cb3     = (const float*)d_in[10];
  const float* cw4     = (const float*)d_in[11];
  const float* cb4     = (const float*)d_in[12];
  const float* w1      = (const float*)d_in[13];
  const float* w2      = (const float*)d_in[14];
  const float* w3      = (const float*)d_in[15];
  const float* w4      = (const float*)d_in[16];
  const int*   perms   = (const int*)d_in[17];

  float* out = (float*)d_out;

  fused_all<<<1984, 256, 0, stream>>>(f1, f2, f3, f4, cw1, cb1, cw2, cb2,
                                      cw3, cb3, cw4, cb4, x_final, w1, w2, w3, w4,
                                      perms, out);
}

// Round 19
// 47.497 us; speedup vs baseline: 1.5423x; 1.2671x over previous
//
#include <hip/hip_runtime.h>
#include <hip/hip_bf16.h>
#include <cstddef>

typedef __attribute__((ext_vector_type(8))) short bf16x8;
typedef __attribute__((ext_vector_type(4))) float f32x4;

__device__ __forceinline__ float4 ld4(const float* p) { return *(const float4*)p; }
__device__ __forceinline__ unsigned short f2bf(float v) {
  __hip_bfloat16 h = __float2bfloat16(v);
  return *(unsigned short*)&h;
}

// 2x bilinear upsample of one 2x2 quad (three halo-resolved source rows).
__device__ __forceinline__ void up_quad_rows(const float* __restrict__ s0,
                                             const float* __restrict__ s1,
                                             const float* __restrict__ s2,
                                             int qx, int W, float* __restrict__ dst, int pitch) {
  int cm = qx > 0 ? qx - 1 : 0, cp = qx < W - 1 ? qx + 1 : W - 1;
  float tA0 = 0.25f * s0[cm] + 0.75f * s0[qx], tA1 = 0.75f * s0[qx] + 0.25f * s0[cp];
  float tB0 = 0.25f * s1[cm] + 0.75f * s1[qx], tB1 = 0.75f * s1[qx] + 0.25f * s1[cp];
  float tC0 = 0.25f * s2[cm] + 0.75f * s2[qx], tC1 = 0.75f * s2[qx] + 0.25f * s2[cp];
  *(float2*)dst = make_float2(0.25f * tA0 + 0.75f * tB0, 0.25f * tA1 + 0.75f * tB1);
  *(float2*)(dst + pitch) = make_float2(0.75f * tB0 + 0.25f * tC0, 0.75f * tB1 + 0.25f * tC1);
}

// 2x upsample of TWO adjacent quads (qx0 even): 4-wide x 2-row patch, float4 stores.
__device__ __forceinline__ void up_quad2(const float* __restrict__ s0,
                                         const float* __restrict__ s1,
                                         const float* __restrict__ s2,
                                         int qx0, int W, float* __restrict__ dst, int pitch) {
  int cm = qx0 > 0 ? qx0 - 1 : 0;
  int c2 = qx0 + 2 < W ? qx0 + 2 : W - 1;
  float Am = s0[cm], A0 = s0[qx0], A1 = s0[qx0 + 1], A2 = s0[c2];
  float Bm = s1[cm], B0 = s1[qx0], B1 = s1[qx0 + 1], B2 = s1[c2];
  float Cm = s2[cm], C0 = s2[qx0], C1 = s2[qx0 + 1], C2 = s2[c2];
  float hA0 = 0.25f * Am + 0.75f * A0, hA1 = 0.75f * A0 + 0.25f * A1;
  float hA2 = 0.25f * A0 + 0.75f * A1, hA3 = 0.75f * A1 + 0.25f * A2;
  float hB0 = 0.25f * Bm + 0.75f * B0, hB1 = 0.75f * B0 + 0.25f * B1;
  float hB2 = 0.25f * B0 + 0.75f * B1, hB3 = 0.75f * B1 + 0.25f * B2;
  float hC0 = 0.25f * Cm + 0.75f * C0, hC1 = 0.75f * C0 + 0.25f * C1;
  float hC2 = 0.25f * C0 + 0.75f * C1, hC3 = 0.75f * C1 + 0.25f * C2;
  *(float4*)dst = make_float4(0.25f * hA0 + 0.75f * hB0, 0.25f * hA1 + 0.75f * hB1,
                              0.25f * hA2 + 0.75f * hB2, 0.25f * hA3 + 0.75f * hB3);
  *(float4*)(dst + pitch) = make_float4(0.75f * hB0 + 0.25f * hC0, 0.75f * hB1 + 0.25f * hC1,
                                        0.75f * hB2 + 0.25f * hC2, 0.75f * hB3 + 0.25f * hC3);
}

// ---------------------------------------------------------------------------
// setup256 (R9/R10 verbatim): transposes to bf16 [p][c] + weight bf16 + copies.
// ---------------------------------------------------------------------------
__global__ void __launch_bounds__(256)
setup256(const float* __restrict__ f1, const float* __restrict__ f2,
         const float* __restrict__ f3, const float* __restrict__ f4,
         const float* __restrict__ cw1, const float* __restrict__ cw2,
         const float* __restrict__ cw3, const float* __restrict__ cw4,
         const float* __restrict__ xf, const float* __restrict__ w1,
         const float* __restrict__ w2, const float* __restrict__ w3,
         const float* __restrict__ w4s,
         unsigned short* __restrict__ f1T, unsigned short* __restrict__ f2T,
         unsigned short* __restrict__ f3T, unsigned short* __restrict__ inT,
         unsigned short* __restrict__ w1b, unsigned short* __restrict__ w2b,
         unsigned short* __restrict__ w3b, unsigned short* __restrict__ w4b,
         float* __restrict__ out) {
  __shared__ unsigned short stile[12800];
  const int bid = blockIdx.x, tid = threadIdx.x;

  if (bid < 256) {
    const int b = bid >> 2, c0 = (bid & 3) * 128;
    const float* src = f4 + ((size_t)b * 512 + c0) * 49;
    for (int i = tid; i < 128 * 49; i += 256) {
      int ci = i / 49, p = i - ci * 49;
      stile[ci * 50 + p] = f2bf(src[i]);
    }
    __syncthreads();
    unsigned short* dst = inT + (size_t)b * 64 * 512 + c0;
    for (int i = tid; i < 64 * 128; i += 256) {
      int p = i >> 7, ci = i & 127;
      dst[(size_t)p * 512 + ci] = (p < 49) ? stile[ci * 50 + p] : (unsigned short)0;
    }
  } else if (bid < 512) {
    const int t = bid - 256, b = t >> 2, q = t & 3;
    const float* src = f1 + (size_t)b * 64 * 784 + q * 196;
    for (int i = tid; i < 64 * 196; i += 256) {
      int ci = i / 196, px = i - ci * 196;
      stile[ci * 196 + px] = f2bf(src[(size_t)ci * 784 + px]);
    }
    __syncthreads();
    unsigned short* dst = f1T + ((size_t)b * 784 + q * 196) * 64;
    for (int i = tid; i < 196 * 8; i += 256) {
      int p = i >> 3, cg = (i & 7) * 8;
      unsigned short tmp[8];
#pragma unroll
      for (int k = 0; k < 8; ++k) tmp[k] = stile[(cg + k) * 196 + p];
      *(ushort4*)(dst + (size_t)p * 64 + cg) = *(ushort4*)tmp;
      *(ushort4*)(dst + (size_t)p * 64 + cg + 4) = *(ushort4*)(tmp + 4);
    }
  } else if (bid < 640) {
    const int t = bid - 512, b = t >> 1, h = t & 1;
    const float* src = f2 + (size_t)b * 128 * 196 + h * 98;
    for (int i = tid; i < 128 * 98; i += 256) {
      int ci = i / 98, px = i - ci * 98;
      stile[ci * 98 + px] = f2bf(src[(size_t)ci * 196 + px]);
    }
    __syncthreads();
    unsigned short* dst = f2T + ((size_t)b * 196 + h * 98) * 128;
    for (int i = tid; i < 98 * 16; i += 256) {
      int p = i >> 4, cg = (i & 15) * 8;
      unsigned short tmp[8];
#pragma unroll
      for (int k = 0; k < 8; ++k) tmp[k] = stile[(cg + k) * 98 + p];
      *(ushort4*)(dst + (size_t)p * 128 + cg) = *(ushort4*)tmp;
      *(ushort4*)(dst + (size_t)p * 128 + cg + 4) = *(ushort4*)(tmp + 4);
    }
  } else if (bid < 704) {
    const int b = bid - 640;
    const float* src = f3 + (size_t)b * 128 * 49;
    for (int i = tid; i < 128 * 49; i += 256) {
      int ci = i / 49, px = i - ci * 49;
      stile[ci * 49 + px] = f2bf(src[i]);
    }
    __syncthreads();
    unsigned short* dst = f3T + (size_t)b * 64 * 128;
    for (int i = tid; i < 64 * 16; i += 256) {
      int p = i >> 4, cg = (i & 15) * 8;
      unsigned short tmp[8];
#pragma unroll
      for (int k = 0; k < 8; ++k) tmp[k] = (p < 49) ? stile[(cg + k) * 49 + p] : (unsigned short)0;
      *(ushort4*)(dst + (size_t)p * 128 + cg) = *(ushort4*)tmp;
      *(ushort4*)(dst + (size_t)p * 128 + cg + 4) = *(ushort4*)(tmp + 4);
    }
  } else {
    int idx = (bid - 704) * 256 + tid;
    const int stride = 64 * 256;
#define CVT(DST, SRC, N)                                          \
    for (int i = idx; i < (N); i += stride) {                     \
      float4 v = ld4((SRC) + 4 * i);                              \
      ushort4 u;                                                  \
      u.x = f2bf(v.x); u.y = f2bf(v.y); u.z = f2bf(v.z); u.w = f2bf(v.w); \
      *(ushort4*)((DST) + 4 * i) = u;                             \
    }
    CVT(w4b, cw4, 65536)
    CVT(w1b, cw1, 1024)
    CVT(w2b, cw2, 4096)
    CVT(w3b, cw3, 8192)
#undef CVT
    float4* o4 = (float4*)out;
    const size_t W1 = 6029312;  // o_w1 offset in float4s
    for (int i = idx; i < 8192; i += stride) o4[i] = ((const float4*)xf)[i];
    for (int i = idx; i < 50176; i += stride) o4[W1 + i] = ((const float4*)w1)[i];
    for (int i = idx; i < 25088; i += stride) o4[W1 + 50176 + i] = ((const float4*)w2)[i];
    for (int i = idx; i < 12544; i += stride) o4[W1 + 75264 + i] = ((const float4*)w3)[i];
    for (int i = idx; i < 6272; i += stride) o4[W1 + 87808 + i] = ((const float4*)w4s)[i];
  }
}

struct P1M { float ct[16][252]; int inv[4][16]; };
struct C2M { float ct[32][126]; };
struct C3M { float ct[64][49]; };
union SmemM { P1M p1; C2M c2; C3M c3; };

// Balanced XCD-local decode (R13-proven).
__device__ __forceinline__ int2 xcd_decode(int d, int wpb_log) {
  int xcd = d & 7;
  int i = (d >> 3) & ((1 << wpb_log) - 1);
  int b = (((d >> (3 + wpb_log)) << 3) | xcd);
  return make_int2(b, i);
}

// ---------------------------------------------------------------------------
// fused_all: 1984 blocks x 256 thr. R15 decode/geometry; fragments are single
// 16B dwordx4 loads from packed bf16 operands (R10-proven addressing).
//  [0,128)     conv4 | [128,1152) perm1 | [1152,1664) conv2
//  [1664,1920) conv3 | [1920,1984) copies second half is done in setup
// ---------------------------------------------------------------------------
__global__ void __launch_bounds__(256)
fused_all(const unsigned short* __restrict__ f1T, const unsigned short* __restrict__ f2T,
          const unsigned short* __restrict__ f3T, const unsigned short* __restrict__ inT,
          const unsigned short* __restrict__ w1b, const unsigned short* __restrict__ w2b,
          const unsigned short* __restrict__ w3b, const unsigned short* __restrict__ w4b,
          const float* __restrict__ cb1, const float* __restrict__ cb2,
          const float* __restrict__ cb3, const float* __restrict__ cb4,
          const int* __restrict__ perms, float* __restrict__ out) {
  __shared__ SmemM sm;
  const int raw = blockIdx.x, tid = threadIdx.x;
  const int wave = tid >> 6, lane = tid & 63;
  const int l15 = lane & 15, lg = lane >> 4;
  float* o_aux1 = out + 32768;
  float* o_aux2 = o_aux1 + 12845056;
  float* o_aux3 = o_aux2 + 6422528;
  float* o_aux4 = o_aux3 + 3211264;

  if (raw < 128) {
    // ============ conv4: wave = 64 och (M=4), packed operands ============
    int2 bi = xcd_decode(raw, 1);
    const int b = bi.x;
    const int ob = bi.y * 256 + wave * 64;

    f32x4 acc[4][4];
#pragma unroll
    for (int mi = 0; mi < 4; ++mi) {
      float bv0 = cb4[ob + mi * 16 + lg * 4 + 0], bv1 = cb4[ob + mi * 16 + lg * 4 + 1];
      float bv2 = cb4[ob + mi * 16 + lg * 4 + 2], bv3 = cb4[ob + mi * 16 + lg * 4 + 3];
#pragma unroll
      for (int n = 0; n < 4; ++n) {
        acc[mi][n][0] = bv0; acc[mi][n][1] = bv1; acc[mi][n][2] = bv2; acc[mi][n][3] = bv3;
      }
    }
    const unsigned short* bp = inT + (size_t)b * 64 * 512 + (size_t)l15 * 512 + lg * 8;
#pragma unroll 2
    for (int k0 = 0; k0 < 512; k0 += 32) {
      bf16x8 A0 = *(const bf16x8*)(w4b + (size_t)(ob + 0 + l15) * 512 + k0 + lg * 8);
      bf16x8 A1 = *(const bf16x8*)(w4b + (size_t)(ob + 16 + l15) * 512 + k0 + lg * 8);
      bf16x8 A2 = *(const bf16x8*)(w4b + (size_t)(ob + 32 + l15) * 512 + k0 + lg * 8);
      bf16x8 A3 = *(const bf16x8*)(w4b + (size_t)(ob + 48 + l15) * 512 + k0 + lg * 8);
      bf16x8 B0 = *(const bf16x8*)(bp + k0);
      bf16x8 B1 = *(const bf16x8*)(bp + 16 * 512 + k0);
      bf16x8 B2 = *(const bf16x8*)(bp + 32 * 512 + k0);
      bf16x8 B3 = *(const bf16x8*)(bp + 48 * 512 + k0);
      acc[0][0] = __builtin_amdgcn_mfma_f32_16x16x32_bf16(A0, B0, acc[0][0], 0, 0, 0);
      acc[0][1] = __builtin_amdgcn_mfma_f32_16x16x32_bf16(A0, B1, acc[0][1], 0, 0, 0);
      acc[0][2] = __builtin_amdgcn_mfma_f32_16x16x32_bf16(A0, B2, acc[0][2], 0, 0, 0);
      acc[0][3] = __builtin_amdgcn_mfma_f32_16x16x32_bf16(A0, B3, acc[0][3], 0, 0, 0);
      acc[1][0] = __builtin_amdgcn_mfma_f32_16x16x32_bf16(A1, B0, acc[1][0], 0, 0, 0);
      acc[1][1] = __builtin_amdgcn_mfma_f32_16x16x32_bf16(A1, B1, acc[1][1], 0, 0, 0);
      acc[1][2] = __builtin_amdgcn_mfma_f32_16x16x32_bf16(A1, B2, acc[1][2], 0, 0, 0);
      acc[1][3] = __builtin_amdgcn_mfma_f32_16x16x32_bf16(A1, B3, acc[1][3], 0, 0, 0);
      acc[2][0] = __builtin_amdgcn_mfma_f32_16x16x32_bf16(A2, B0, acc[2][0], 0, 0, 0);
      acc[2][1] = __builtin_amdgcn_mfma_f32_16x16x32_bf16(A2, B1, acc[2][1], 0, 0, 0);
      acc[2][2] = __builtin_amdgcn_mfma_f32_16x16x32_bf16(A2, B2, acc[2][2], 0, 0, 0);
      acc[2][3] = __builtin_amdgcn_mfma_f32_16x16x32_bf16(A2, B3, acc[2][3], 0, 0, 0);
      acc[3][0] = __builtin_amdgcn_mfma_f32_16x16x32_bf16(A3, B0, acc[3][0], 0, 0, 0);
      acc[3][1] = __builtin_amdgcn_mfma_f32_16x16x32_bf16(A3, B1, acc[3][1], 0, 0, 0);
      acc[3][2] = __builtin_amdgcn_mfma_f32_16x16x32_bf16(A3, B2, acc[3][2], 0, 0, 0);
      acc[3][3] = __builtin_amdgcn_mfma_f32_16x16x32_bf16(A3, B3, acc[3][3], 0, 0, 0);
    }
    float* outb = o_aux4 + (size_t)b * 25088;
#pragma unroll
    for (int mi = 0; mi < 4; ++mi) {
#pragma unroll
      for (int n = 0; n < 4; ++n) {
        int p = n * 16 + l15;
        if (p < 49) {
#pragma unroll
          for (int r = 0; r < 4; ++r) {
            int o = ob + mi * 16 + lg * 4 + r;
            outb[(size_t)o * 49 + p] = acc[mi][n][r];
          }
        }
      }
    }
  } else if (raw < 1152) {
    // ============ perm1: 16 och x 7-row chunk, packed operands ============
    int2 bi = xcd_decode(raw - 128, 4);
    const int b = bi.x;
    const int o0 = (bi.y >> 2) * 16;
    const int r0 = (bi.y & 3) * 7, base = r0 - 1;

    if (tid >= 128 && tid < 192) {
      int t2 = tid - 128;
      int i = t2 >> 4, cl = t2 & 15;
      int c = o0 + cl;
      int r = 0;
      for (int j = 0; j < 64; ++j)
        if (perms[i * 64 + j] == c) r = j;
      sm.p1.inv[i][cl] = r;
    }

    const unsigned short* bp[4];
#pragma unroll
    for (int j = 0; j < 4; ++j) {
      int praw = wave * 64 + j * 16 + l15;
      int p = praw < 251 ? praw : 251;
      int lr = p / 28, x = p - lr * 28;
      int sr = base + lr;
      sr = sr < 0 ? 0 : (sr > 27 ? 27 : sr);
      bp[j] = f1T + ((size_t)b * 784 + sr * 28 + x) * 64 + lg * 8;
    }
    f32x4 acc[4];
    {
      float bv0 = cb1[o0 + lg * 4 + 0], bv1 = cb1[o0 + lg * 4 + 1];
      float bv2 = cb1[o0 + lg * 4 + 2], bv3 = cb1[o0 + lg * 4 + 3];
#pragma unroll
      for (int j = 0; j < 4; ++j) {
        acc[j][0] = bv0; acc[j][1] = bv1; acc[j][2] = bv2; acc[j][3] = bv3;
      }
    }
    const unsigned short* ap = w1b + (size_t)(o0 + l15) * 64 + lg * 8;
#pragma unroll
    for (int ks = 0; ks < 2; ++ks) {
      bf16x8 A = *(const bf16x8*)(ap + ks * 32);
#pragma unroll
      for (int j = 0; j < 4; ++j) {
        bf16x8 B = *(const bf16x8*)(bp[j] + ks * 32);
        acc[j] = __builtin_amdgcn_mfma_f32_16x16x32_bf16(A, B, acc[j], 0, 0, 0);
      }
    }
#pragma unroll
    for (int j = 0; j < 4; ++j) {
      int praw = wave * 64 + j * 16 + l15;
      if (praw < 252) {
#pragma unroll
        for (int r = 0; r < 4; ++r) sm.p1.ct[lg * 4 + r][praw] = acc[j][r];
      }
    }
    __syncthreads();

    const size_t obase = (size_t)b * 200704;
    for (int i = tid; i < 1568; i += 256) {
      int cl = i / 98;
      int rem = i - cl * 98;
      int ly = rem / 14, pr = rem - ly * 14;
      int qx0 = 2 * pr;
      int qy = r0 + ly;
      int lr = ly + 1;
      int qi = ((qy >= 14) ? 2 : 0) + ((qx0 >= 14) ? 1 : 0);
      int j = sm.p1.inv[qi][cl];
      float* dst = o_aux1 + obase + (size_t)j * 3136 + (size_t)(2 * qy) * 56 + 2 * qx0;
      up_quad2(&sm.p1.ct[cl][(lr - 1) * 28], &sm.p1.ct[cl][lr * 28],
               &sm.p1.ct[cl][(lr + 1) * 28], qx0, 28, dst, 56);
    }
  } else if (raw < 1664) {
    // ============ conv2: 32 och x 7-row chunk, packed operands ============
    int2 bi = xcd_decode(raw - 1152, 3);
    const int b = bi.x;
    const int o0 = (bi.y >> 1) * 32;
    const int r0 = (bi.y & 1) * 7, base = r0 - 1;
    const int og = wave >> 1, nt = wave & 1;
    const int om = o0 + og * 16;

    const unsigned short* bp[4];
#pragma unroll
    for (int j = 0; j < 4; ++j) {
      int praw = nt * 64 + j * 16 + l15;
      int p = praw < 125 ? praw : 125;
      int lr = p / 14, x = p - lr * 14;
      int sr = base + lr;
      sr = sr < 0 ? 0 : (sr > 13 ? 13 : sr);
      bp[j] = f2T + ((size_t)b * 196 + sr * 14 + x) * 128 + lg * 8;
    }
    f32x4 acc[4];
    {
      float bv0 = cb2[om + lg * 4 + 0], bv1 = cb2[om + lg * 4 + 1];
      float bv2 = cb2[om + lg * 4 + 2], bv3 = cb2[om + lg * 4 + 3];
#pragma unroll
      for (int j = 0; j < 4; ++j) {
        acc[j][0] = bv0; acc[j][1] = bv1; acc[j][2] = bv2; acc[j][3] = bv3;
      }
    }
    const unsigned short* ap = w2b + (size_t)(om + l15) * 128 + lg * 8;
#pragma unroll
    for (int ks = 0; ks < 4; ++ks) {
      bf16x8 A = *(const bf16x8*)(ap + ks * 32);
#pragma unroll
      for (int j = 0; j < 4; ++j) {
        bf16x8 B = *(const bf16x8*)(bp[j] + ks * 32);
        acc[j] = __builtin_amdgcn_mfma_f32_16x16x32_bf16(A, B, acc[j], 0, 0, 0);
      }
    }
#pragma unroll
    for (int j = 0; j < 4; ++j) {
      int praw = nt * 64 + j * 16 + l15;
      if (praw < 126) {
#pragma unroll
        for (int r = 0; r < 4; ++r) sm.c2.ct[og * 16 + lg * 4 + r][praw] = acc[j][r];
      }
    }
    __syncthreads();

    const size_t obase = (size_t)b * 100352;
    for (int i = tid; i < 1568; i += 256) {
      int cl = i / 49;
      int rem = i - cl * 49;
      int ly = rem / 7, pr = rem - ly * 7;
      int qx0 = 2 * pr;
      int qy = r0 + ly;
      int lr = ly + 1;
      float* dst = o_aux2 + obase + (size_t)(o0 + cl) * 784 + (size_t)(2 * qy) * 28 + 2 * qx0;
      up_quad2(&sm.c2.ct[cl][(lr - 1) * 14], &sm.c2.ct[cl][lr * 14],
               &sm.c2.ct[cl][(lr + 1) * 14], qx0, 14, dst, 28);
    }
  } else if (raw < 1920) {
    // ============ conv3: 64 och, packed operands ============
    int2 bi = xcd_decode(raw - 1664, 2);
    const int b = bi.x;
    const int o0 = bi.y * 64;
    const int om = o0 + wave * 16;

    const unsigned short* bp[4];
#pragma unroll
    for (int j = 0; j < 4; ++j) {
      int p = j * 16 + l15;  // f3T zero-padded to 64 rows
      bp[j] = f3T + ((size_t)b * 64 + p) * 128 + lg * 8;
    }
    f32x4 acc[4];
    {
      float bv0 = cb3[om + lg * 4 + 0], bv1 = cb3[om + lg * 4 + 1];
      float bv2 = cb3[om + lg * 4 + 2], bv3 = cb3[om + lg * 4 + 3];
#pragma unroll
      for (int j = 0; j < 4; ++j) {
        acc[j][0] = bv0; acc[j][1] = bv1; acc[j][2] = bv2; acc[j][3] = bv3;
      }
    }
    const unsigned short* ap = w3b + (size_t)(om + l15) * 128 + lg * 8;
#pragma unroll
    for (int ks = 0; ks < 4; ++ks) {
      bf16x8 A = *(const bf16x8*)(ap + ks * 32);
#pragma unroll
      for (int j = 0; j < 4; ++j) {
        bf16x8 B = *(const bf16x8*)(bp[j] + ks * 32);
        acc[j] = __builtin_amdgcn_mfma_f32_16x16x32_bf16(A, B, acc[j], 0, 0, 0);
      }
    }
#pragma unroll
    for (int j = 0; j < 4; ++j) {
      int p = j * 16 + l15;
      if (p < 49) {
#pragma unroll
        for (int r = 0; r < 4; ++r) sm.c3.ct[wave * 16 + lg * 4 + r][p] = acc[j][r];
      }
    }
    __syncthreads();

    const size_t obase = (size_t)b * 50176;
    for (int i = tid; i < 64 * 49; i += 256) {
      int cl = i / 49;
      int q = i - cl * 49;
      int qy = q / 7, qx = q - qy * 7;
      int rm = qy > 0 ? qy - 1 : 0, rp = qy < 6 ? qy + 1 : 6;
      float* dst = o_aux3 + obase + (size_t)(o0 + cl) * 196 + (size_t)(2 * qy) * 14 + 2 * qx;
      up_quad_rows(&sm.c3.ct[cl][rm * 7], &sm.c3.ct[cl][qy * 7], &sm.c3.ct[cl][rp * 7],
                   qx, 7, dst, 14);
    }
  }
  // [1920,1984): no-op spill blocks (copies done in setup256) — keep grid
  // multiple-of-8 alignment for the decode; they exit immediately.
}

extern "C" void kernel_launch(void* const* d_in, const int* in_sizes, int n_in,
                              void* d_out, int out_size, void* d_ws, size_t ws_size,
                              hipStream_t stream) {
  const float* f1      = (const float*)d_in[0];
  const float* f2      = (const float*)d_in[1];
  const float* f3      = (const float*)d_in[2];
  const float* f4      = (const float*)d_in[3];
  const float* x_final = (const float*)d_in[4];
  const float* cw1     = (const float*)d_in[5];
  const float* cb1     = (const float*)d_in[6];
  const float* cw2     = (const float*)d_in[7];
  const float* cb2     = (const float*)d_in[8];
  const float* cw3     = (const float*)d_in[9];
  const float* cb3     = (const float*)d_in[10];
  const float* cw4     = (const float*)d_in[11];
  const float* cb4     = (const float*)d_in[12];
  const float* w1      = (const float*)d_in[13];
  const float* w2      = (const float*)d_in[14];
  const float* w3      = (const float*)d_in[15];
  const float* w4      = (const float*)d_in[16];
  const int*   perms   = (const int*)d_in[17];

  float* out = (float*)d_out;

  unsigned short* ws  = (unsigned short*)d_ws;
  unsigned short* inT = ws;                      // 64*64*512      = 2,097,152
  unsigned short* f1T = inT + 2097152;           // 64*784*64      = 3,211,264
  unsigned short* f2T = f1T + 3211264;           // 64*196*128     = 1,605,632
  unsigned short* f3T = f2T + 1605632;           // 64*64*128      =   524,288
  unsigned short* w4b = f3T + 524288;            // 512*512        =   262,144
  unsigned short* w1b = w4b + 262144;            // 64*64          =     4,096
  unsigned short* w2b = w1b + 4096;              // 128*128        =    16,384
  unsigned short* w3b = w2b + 16384;             // 256*128        =    32,768

  setup256<<<768, 256, 0, stream>>>(f1, f2, f3, f4, cw1, cw2, cw3, cw4,
                                    x_final, w1, w2, w3, w4,
                                    f1T, f2T, f3T, inT, w1b, w2b, w3b, w4b, out);
  fused_all<<<1920, 256, 0, stream>>>(f1T, f2T, f3T, inT, w1b, w2b, w3b, w4b,
                                      cb1, cb2, cb3, cb4, perms, out);
}

// Round 20
// 46.898 us; speedup vs baseline: 1.5620x; 1.0128x over previous
//
#include <hip/hip_runtime.h>
#include <hip/hip_bf16.h>
#include <cstddef>

typedef __attribute__((ext_vector_type(8))) short bf16x8;
typedef __attribute__((ext_vector_type(4))) float f32x4;

__device__ __forceinline__ float4 ld4(const float* p) { return *(const float4*)p; }
__device__ __forceinline__ unsigned short f2bf(float v) {
  __hip_bfloat16 h = __float2bfloat16(v);
  return *(unsigned short*)&h;
}

// 2x bilinear upsample of one 2x2 quad (three halo-resolved source rows).
__device__ __forceinline__ void up_quad_rows(const float* __restrict__ s0,
                                             const float* __restrict__ s1,
                                             const float* __restrict__ s2,
                                             int qx, int W, float* __restrict__ dst, int pitch) {
  int cm = qx > 0 ? qx - 1 : 0, cp = qx < W - 1 ? qx + 1 : W - 1;
  float tA0 = 0.25f * s0[cm] + 0.75f * s0[qx], tA1 = 0.75f * s0[qx] + 0.25f * s0[cp];
  float tB0 = 0.25f * s1[cm] + 0.75f * s1[qx], tB1 = 0.75f * s1[qx] + 0.25f * s1[cp];
  float tC0 = 0.25f * s2[cm] + 0.75f * s2[qx], tC1 = 0.75f * s2[qx] + 0.25f * s2[cp];
  *(float2*)dst = make_float2(0.25f * tA0 + 0.75f * tB0, 0.25f * tA1 + 0.75f * tB1);
  *(float2*)(dst + pitch) = make_float2(0.75f * tB0 + 0.25f * tC0, 0.75f * tB1 + 0.25f * tC1);
}

// 2x upsample of TWO adjacent quads (qx0 even): 4-wide x 2-row patch, float4 stores.
__device__ __forceinline__ void up_quad2(const float* __restrict__ s0,
                                         const float* __restrict__ s1,
                                         const float* __restrict__ s2,
                                         int qx0, int W, float* __restrict__ dst, int pitch) {
  int cm = qx0 > 0 ? qx0 - 1 : 0;
  int c2 = qx0 + 2 < W ? qx0 + 2 : W - 1;
  float Am = s0[cm], A0 = s0[qx0], A1 = s0[qx0 + 1], A2 = s0[c2];
  float Bm = s1[cm], B0 = s1[qx0], B1 = s1[qx0 + 1], B2 = s1[c2];
  float Cm = s2[cm], C0 = s2[qx0], C1 = s2[qx0 + 1], C2 = s2[c2];
  float hA0 = 0.25f * Am + 0.75f * A0, hA1 = 0.75f * A0 + 0.25f * A1;
  float hA2 = 0.25f * A0 + 0.75f * A1, hA3 = 0.75f * A1 + 0.25f * A2;
  float hB0 = 0.25f * Bm + 0.75f * B0, hB1 = 0.75f * B0 + 0.25f * B1;
  float hB2 = 0.25f * B0 + 0.75f * B1, hB3 = 0.75f * B1 + 0.25f * B2;
  float hC0 = 0.25f * Cm + 0.75f * C0, hC1 = 0.75f * C0 + 0.25f * C1;
  float hC2 = 0.25f * C0 + 0.75f * C1, hC3 = 0.75f * C1 + 0.25f * C2;
  *(float4*)dst = make_float4(0.25f * hA0 + 0.75f * hB0, 0.25f * hA1 + 0.75f * hB1,
                              0.25f * hA2 + 0.75f * hB2, 0.25f * hA3 + 0.75f * hB3);
  *(float4*)(dst + pitch) = make_float4(0.75f * hB0 + 0.25f * hC0, 0.75f * hB1 + 0.25f * hC1,
                                        0.75f * hB2 + 0.25f * hC2, 0.75f * hB3 + 0.25f * hC3);
}

// ---------------------------------------------------------------------------
// setup256: 1408 blocks, fine-grained for short critical path.
//  [0,512)     inT : f4 -> [b][p(64,pad0)][c512] bf16; (b, 64-ch chunk)
//  [512,1024)  f1T : f1 -> [b][p784][c64] bf16; (b, 98-px chunk)
//  [1024,1280) f2T : f2 -> [b][p196][c128] bf16; (b, 49-px chunk)
//  [1280,1344) f3T : f3 -> [b][p(64,pad0)][c128] bf16; per b
//  [1344,1408) weights -> bf16
// (output copies moved to fused_all spill blocks — no dependency on setup)
// ---------------------------------------------------------------------------
__global__ void __launch_bounds__(256)
setup256(const float* __restrict__ f1, const float* __restrict__ f2,
         const float* __restrict__ f3, const float* __restrict__ f4,
         const float* __restrict__ cw1, const float* __restrict__ cw2,
         const float* __restrict__ cw3, const float* __restrict__ cw4,
         unsigned short* __restrict__ f1T, unsigned short* __restrict__ f2T,
         unsigned short* __restrict__ f3T, unsigned short* __restrict__ inT,
         unsigned short* __restrict__ w1b, unsigned short* __restrict__ w2b,
         unsigned short* __restrict__ w3b, unsigned short* __restrict__ w4b) {
  __shared__ unsigned short stile[12800];
  const int bid = blockIdx.x, tid = threadIdx.x;

  if (bid < 512) {
    // ---- inT: (b, 64-ch chunk) ----
    const int b = bid >> 3, c0 = (bid & 7) * 64;
    const float* src = f4 + ((size_t)b * 512 + c0) * 49;
    for (int i = tid; i < 64 * 49; i += 256) {
      int ci = i / 49, p = i - ci * 49;
      stile[ci * 50 + p] = f2bf(src[i]);
    }
    __syncthreads();
    unsigned short* dst = inT + (size_t)b * 32768 + c0;
    for (int i = tid; i < 64 * 64; i += 256) {
      int p = i >> 6, ci = i & 63;
      dst[(size_t)p * 512 + ci] = (p < 49) ? stile[ci * 50 + p] : (unsigned short)0;
    }
  } else if (bid < 1024) {
    // ---- f1T: (b, 98-px chunk) ----
    const int t = bid - 512, b = t >> 3, q = t & 7;
    const float* src = f1 + (size_t)b * 50176 + q * 98;
    for (int i = tid; i < 64 * 98; i += 256) {
      int ci = i / 98, px = i - ci * 98;
      stile[ci * 98 + px] = f2bf(src[(size_t)ci * 784 + px]);
    }
    __syncthreads();
    unsigned short* dst = f1T + ((size_t)b * 784 + q * 98) * 64;
    for (int i = tid; i < 98 * 8; i += 256) {
      int p = i >> 3, cg = (i & 7) * 8;
      unsigned short tmp[8];
#pragma unroll
      for (int k = 0; k < 8; ++k) tmp[k] = stile[(cg + k) * 98 + p];
      *(ushort4*)(dst + (size_t)p * 64 + cg) = *(ushort4*)tmp;
      *(ushort4*)(dst + (size_t)p * 64 + cg + 4) = *(ushort4*)(tmp + 4);
    }
  } else if (bid < 1280) {
    // ---- f2T: (b, 49-px chunk) ----
    const int t = bid - 1024, b = t >> 2, q = t & 3;
    const float* src = f2 + (size_t)b * 25088 + q * 49;
    for (int i = tid; i < 128 * 49; i += 256) {
      int ci = i / 49, px = i - ci * 49;
      stile[ci * 49 + px] = f2bf(src[(size_t)ci * 196 + px]);
    }
    __syncthreads();
    unsigned short* dst = f2T + ((size_t)b * 196 + q * 49) * 128;
    for (int i = tid; i < 49 * 16; i += 256) {
      int p = i >> 4, cg = (i & 15) * 8;
      unsigned short tmp[8];
#pragma unroll
      for (int k = 0; k < 8; ++k) tmp[k] = stile[(cg + k) * 49 + p];
      *(ushort4*)(dst + (size_t)p * 128 + cg) = *(ushort4*)tmp;
      *(ushort4*)(dst + (size_t)p * 128 + cg + 4) = *(ushort4*)(tmp + 4);
    }
  } else if (bid < 1344) {
    // ---- f3T: per b, pad p to 64 ----
    const int b = bid - 1280;
    const float* src = f3 + (size_t)b * 6272;
    for (int i = tid; i < 128 * 49; i += 256) {
      int ci = i / 49, px = i - ci * 49;
      stile[ci * 49 + px] = f2bf(src[i]);
    }
    __syncthreads();
    unsigned short* dst = f3T + (size_t)b * 8192;
    for (int i = tid; i < 64 * 16; i += 256) {
      int p = i >> 4, cg = (i & 15) * 8;
      unsigned short tmp[8];
#pragma unroll
      for (int k = 0; k < 8; ++k) tmp[k] = (p < 49) ? stile[(cg + k) * 49 + p] : (unsigned short)0;
      *(ushort4*)(dst + (size_t)p * 128 + cg) = *(ushort4*)tmp;
      *(ushort4*)(dst + (size_t)p * 128 + cg + 4) = *(ushort4*)(tmp + 4);
    }
  } else {
    // ---- weight bf16 conversions ----
    int idx = (bid - 1344) * 256 + tid;
    const int stride = 64 * 256;
#define CVT(DST, SRC, N)                                          \
    for (int i = idx; i < (N); i += stride) {                     \
      float4 v = ld4((SRC) + 4 * i);                              \
      ushort4 u;                                                  \
      u.x = f2bf(v.x); u.y = f2bf(v.y); u.z = f2bf(v.z); u.w = f2bf(v.w); \
      *(ushort4*)((DST) + 4 * i) = u;                             \
    }
    CVT(w4b, cw4, 65536)
    CVT(w1b, cw1, 1024)
    CVT(w2b, cw2, 4096)
    CVT(w3b, cw3, 8192)
#undef CVT
  }
}

struct P1M { float ct[16][252]; int inv[4][16]; };
struct C2M { float ct[32][126]; };
struct C3M { float ct[64][49]; };
union SmemM { P1M p1; C2M c2; C3M c3; };

// Balanced XCD-local decode (R13-proven).
__device__ __forceinline__ int2 xcd_decode(int d, int wpb_log) {
  int xcd = d & 7;
  int i = (d >> 3) & ((1 << wpb_log) - 1);
  int b = (((d >> (3 + wpb_log)) << 3) | xcd);
  return make_int2(b, i);
}

// ---------------------------------------------------------------------------
// fused_all: 1984 blocks x 256 thr (R19 bodies).
//  [0,128)     conv4 | [128,1152) perm1 | [1152,1664) conv2
//  [1664,1920) conv3 | [1920,1984) output copies (independent of setup)
// ---------------------------------------------------------------------------
__global__ void __launch_bounds__(256)
fused_all(const unsigned short* __restrict__ f1T, const unsigned short* __restrict__ f2T,
          const unsigned short* __restrict__ f3T, const unsigned short* __restrict__ inT,
          const unsigned short* __restrict__ w1b, const unsigned short* __restrict__ w2b,
          const unsigned short* __restrict__ w3b, const unsigned short* __restrict__ w4b,
          const float* __restrict__ cb1, const float* __restrict__ cb2,
          const float* __restrict__ cb3, const float* __restrict__ cb4,
          const float* __restrict__ xf, const float* __restrict__ w1,
          const float* __restrict__ w2, const float* __restrict__ w3,
          const float* __restrict__ w4s, const int* __restrict__ perms,
          float* __restrict__ out) {
  __shared__ SmemM sm;
  const int raw = blockIdx.x, tid = threadIdx.x;
  const int wave = tid >> 6, lane = tid & 63;
  const int l15 = lane & 15, lg = lane >> 4;
  float* o_aux1 = out + 32768;
  float* o_aux2 = o_aux1 + 12845056;
  float* o_aux3 = o_aux2 + 6422528;
  float* o_aux4 = o_aux3 + 3211264;

  if (raw < 128) {
    // ============ conv4: wave = 64 och (M=4), packed operands ============
    int2 bi = xcd_decode(raw, 1);
    const int b = bi.x;
    const int ob = bi.y * 256 + wave * 64;

    f32x4 acc[4][4];
#pragma unroll
    for (int mi = 0; mi < 4; ++mi) {
      float bv0 = cb4[ob + mi * 16 + lg * 4 + 0], bv1 = cb4[ob + mi * 16 + lg * 4 + 1];
      float bv2 = cb4[ob + mi * 16 + lg * 4 + 2], bv3 = cb4[ob + mi * 16 + lg * 4 + 3];
#pragma unroll
      for (int n = 0; n < 4; ++n) {
        acc[mi][n][0] = bv0; acc[mi][n][1] = bv1; acc[mi][n][2] = bv2; acc[mi][n][3] = bv3;
      }
    }
    const unsigned short* bp = inT + (size_t)b * 32768 + (size_t)l15 * 512 + lg * 8;
#pragma unroll 2
    for (int k0 = 0; k0 < 512; k0 += 32) {
      bf16x8 A0 = *(const bf16x8*)(w4b + (size_t)(ob + 0 + l15) * 512 + k0 + lg * 8);
      bf16x8 A1 = *(const bf16x8*)(w4b + (size_t)(ob + 16 + l15) * 512 + k0 + lg * 8);
      bf16x8 A2 = *(const bf16x8*)(w4b + (size_t)(ob + 32 + l15) * 512 + k0 + lg * 8);
      bf16x8 A3 = *(const bf16x8*)(w4b + (size_t)(ob + 48 + l15) * 512 + k0 + lg * 8);
      bf16x8 B0 = *(const bf16x8*)(bp + k0);
      bf16x8 B1 = *(const bf16x8*)(bp + 16 * 512 + k0);
      bf16x8 B2 = *(const bf16x8*)(bp + 32 * 512 + k0);
      bf16x8 B3 = *(const bf16x8*)(bp + 48 * 512 + k0);
      acc[0][0] = __builtin_amdgcn_mfma_f32_16x16x32_bf16(A0, B0, acc[0][0], 0, 0, 0);
      acc[0][1] = __builtin_amdgcn_mfma_f32_16x16x32_bf16(A0, B1, acc[0][1], 0, 0, 0);
      acc[0][2] = __builtin_amdgcn_mfma_f32_16x16x32_bf16(A0, B2, acc[0][2], 0, 0, 0);
      acc[0][3] = __builtin_amdgcn_mfma_f32_16x16x32_bf16(A0, B3, acc[0][3], 0, 0, 0);
      acc[1][0] = __builtin_amdgcn_mfma_f32_16x16x32_bf16(A1, B0, acc[1][0], 0, 0, 0);
      acc[1][1] = __builtin_amdgcn_mfma_f32_16x16x32_bf16(A1, B1, acc[1][1], 0, 0, 0);
      acc[1][2] = __builtin_amdgcn_mfma_f32_16x16x32_bf16(A1, B2, acc[1][2], 0, 0, 0);
      acc[1][3] = __builtin_amdgcn_mfma_f32_16x16x32_bf16(A1, B3, acc[1][3], 0, 0, 0);
      acc[2][0] = __builtin_amdgcn_mfma_f32_16x16x32_bf16(A2, B0, acc[2][0], 0, 0, 0);
      acc[2][1] = __builtin_amdgcn_mfma_f32_16x16x32_bf16(A2, B1, acc[2][1], 0, 0, 0);
      acc[2][2] = __builtin_amdgcn_mfma_f32_16x16x32_bf16(A2, B2, acc[2][2], 0, 0, 0);
      acc[2][3] = __builtin_amdgcn_mfma_f32_16x16x32_bf16(A2, B3, acc[2][3], 0, 0, 0);
      acc[3][0] = __builtin_amdgcn_mfma_f32_16x16x32_bf16(A3, B0, acc[3][0], 0, 0, 0);
      acc[3][1] = __builtin_amdgcn_mfma_f32_16x16x32_bf16(A3, B1, acc[3][1], 0, 0, 0);
      acc[3][2] = __builtin_amdgcn_mfma_f32_16x16x32_bf16(A3, B2, acc[3][2], 0, 0, 0);
      acc[3][3] = __builtin_amdgcn_mfma_f32_16x16x32_bf16(A3, B3, acc[3][3], 0, 0, 0);
    }
    float* outb = o_aux4 + (size_t)b * 25088;
#pragma unroll
    for (int mi = 0; mi < 4; ++mi) {
#pragma unroll
      for (int n = 0; n < 4; ++n) {
        int p = n * 16 + l15;
        if (p < 49) {
#pragma unroll
          for (int r = 0; r < 4; ++r) {
            int o = ob + mi * 16 + lg * 4 + r;
            outb[(size_t)o * 49 + p] = acc[mi][n][r];
          }
        }
      }
    }
  } else if (raw < 1152) {
    // ============ perm1: 16 och x 7-row chunk, packed operands ============
    int2 bi = xcd_decode(raw - 128, 4);
    const int b = bi.x;
    const int o0 = (bi.y >> 2) * 16;
    const int r0 = (bi.y & 3) * 7, base = r0 - 1;

    if (tid >= 128 && tid < 192) {
      int t2 = tid - 128;
      int i = t2 >> 4, cl = t2 & 15;
      int c = o0 + cl;
      int r = 0;
      for (int j = 0; j < 64; ++j)
        if (perms[i * 64 + j] == c) r = j;
      sm.p1.inv[i][cl] = r;
    }

    const unsigned short* bp[4];
#pragma unroll
    for (int j = 0; j < 4; ++j) {
      int praw = wave * 64 + j * 16 + l15;
      int p = praw < 251 ? praw : 251;
      int lr = p / 28, x = p - lr * 28;
      int sr = base + lr;
      sr = sr < 0 ? 0 : (sr > 27 ? 27 : sr);
      bp[j] = f1T + ((size_t)b * 784 + sr * 28 + x) * 64 + lg * 8;
    }
    f32x4 acc[4];
    {
      float bv0 = cb1[o0 + lg * 4 + 0], bv1 = cb1[o0 + lg * 4 + 1];
      float bv2 = cb1[o0 + lg * 4 + 2], bv3 = cb1[o0 + lg * 4 + 3];
#pragma unroll
      for (int j = 0; j < 4; ++j) {
        acc[j][0] = bv0; acc[j][1] = bv1; acc[j][2] = bv2; acc[j][3] = bv3;
      }
    }
    const unsigned short* ap = w1b + (size_t)(o0 + l15) * 64 + lg * 8;
#pragma unroll
    for (int ks = 0; ks < 2; ++ks) {
      bf16x8 A = *(const bf16x8*)(ap + ks * 32);
#pragma unroll
      for (int j = 0; j < 4; ++j) {
        bf16x8 B = *(const bf16x8*)(bp[j] + ks * 32);
        acc[j] = __builtin_amdgcn_mfma_f32_16x16x32_bf16(A, B, acc[j], 0, 0, 0);
      }
    }
#pragma unroll
    for (int j = 0; j < 4; ++j) {
      int praw = wave * 64 + j * 16 + l15;
      if (praw < 252) {
#pragma unroll
        for (int r = 0; r < 4; ++r) sm.p1.ct[lg * 4 + r][praw] = acc[j][r];
      }
    }
    __syncthreads();

    const size_t obase = (size_t)b * 200704;
    for (int i = tid; i < 1568; i += 256) {
      int cl = i / 98;
      int rem = i - cl * 98;
      int ly = rem / 14, pr = rem - ly * 14;
      int qx0 = 2 * pr;
      int qy = r0 + ly;
      int lr = ly + 1;
      int qi = ((qy >= 14) ? 2 : 0) + ((qx0 >= 14) ? 1 : 0);
      int j = sm.p1.inv[qi][cl];
      float* dst = o_aux1 + obase + (size_t)j * 3136 + (size_t)(2 * qy) * 56 + 2 * qx0;
      up_quad2(&sm.p1.ct[cl][(lr - 1) * 28], &sm.p1.ct[cl][lr * 28],
               &sm.p1.ct[cl][(lr + 1) * 28], qx0, 28, dst, 56);
    }
  } else if (raw < 1664) {
    // ============ conv2: 32 och x 7-row chunk, packed operands ============
    int2 bi = xcd_decode(raw - 1152, 3);
    const int b = bi.x;
    const int o0 = (bi.y >> 1) * 32;
    const int r0 = (bi.y & 1) * 7, base = r0 - 1;
    const int og = wave >> 1, nt = wave & 1;
    const int om = o0 + og * 16;

    const unsigned short* bp[4];
#pragma unroll
    for (int j = 0; j < 4; ++j) {
      int praw = nt * 64 + j * 16 + l15;
      int p = praw < 125 ? praw : 125;
      int lr = p / 14, x = p - lr * 14;
      int sr = base + lr;
      sr = sr < 0 ? 0 : (sr > 13 ? 13 : sr);
      bp[j] = f2T + ((size_t)b * 196 + sr * 14 + x) * 128 + lg * 8;
    }
    f32x4 acc[4];
    {
      float bv0 = cb2[om + lg * 4 + 0], bv1 = cb2[om + lg * 4 + 1];
      float bv2 = cb2[om + lg * 4 + 2], bv3 = cb2[om + lg * 4 + 3];
#pragma unroll
      for (int j = 0; j < 4; ++j) {
        acc[j][0] = bv0; acc[j][1] = bv1; acc[j][2] = bv2; acc[j][3] = bv3;
      }
    }
    const unsigned short* ap = w2b + (size_t)(om + l15) * 128 + lg * 8;
#pragma unroll
    for (int ks = 0; ks < 4; ++ks) {
      bf16x8 A = *(const bf16x8*)(ap + ks * 32);
#pragma unroll
      for (int j = 0; j < 4; ++j) {
        bf16x8 B = *(const bf16x8*)(bp[j] + ks * 32);
        acc[j] = __builtin_amdgcn_mfma_f32_16x16x32_bf16(A, B, acc[j], 0, 0, 0);
      }
    }
#pragma unroll
    for (int j = 0; j < 4; ++j) {
      int praw = nt * 64 + j * 16 + l15;
      if (praw < 126) {
#pragma unroll
        for (int r = 0; r < 4; ++r) sm.c2.ct[og * 16 + lg * 4 + r][praw] = acc[j][r];
      }
    }
    __syncthreads();

    const size_t obase = (size_t)b * 100352;
    for (int i = tid; i < 1568; i += 256) {
      int cl = i / 49;
      int rem = i - cl * 49;
      int ly = rem / 7, pr = rem - ly * 7;
      int qx0 = 2 * pr;
      int qy = r0 + ly;
      int lr = ly + 1;
      float* dst = o_aux2 + obase + (size_t)(o0 + cl) * 784 + (size_t)(2 * qy) * 28 + 2 * qx0;
      up_quad2(&sm.c2.ct[cl][(lr - 1) * 14], &sm.c2.ct[cl][lr * 14],
               &sm.c2.ct[cl][(lr + 1) * 14], qx0, 14, dst, 28);
    }
  } else if (raw < 1920) {
    // ============ conv3: 64 och, packed operands ============
    int2 bi = xcd_decode(raw - 1664, 2);
    const int b = bi.x;
    const int o0 = bi.y * 64;
    const int om = o0 + wave * 16;

    const unsigned short* bp[4];
#pragma unroll
    for (int j = 0; j < 4; ++j) {
      int p = j * 16 + l15;  // f3T zero-padded to 64 rows
      bp[j] = f3T + ((size_t)b * 64 + p) * 128 + lg * 8;
    }
    f32x4 acc[4];
    {
      float bv0 = cb3[om + lg * 4 + 0], bv1 = cb3[om + lg * 4 + 1];
      float bv2 = cb3[om + lg * 4 + 2], bv3 = cb3[om + lg * 4 + 3];
#pragma unroll
      for (int j = 0; j < 4; ++j) {
        acc[j][0] = bv0; acc[j][1] = bv1; acc[j][2] = bv2; acc[j][3] = bv3;
      }
    }
    const unsigned short* ap = w3b + (size_t)(om + l15) * 128 + lg * 8;
#pragma unroll
    for (int ks = 0; ks < 4; ++ks) {
      bf16x8 A = *(const bf16x8*)(ap + ks * 32);
#pragma unroll
      for (int j = 0; j < 4; ++j) {
        bf16x8 B = *(const bf16x8*)(bp[j] + ks * 32);
        acc[j] = __builtin_amdgcn_mfma_f32_16x16x32_bf16(A, B, acc[j], 0, 0, 0);
      }
    }
#pragma unroll
    for (int j = 0; j < 4; ++j) {
      int p = j * 16 + l15;
      if (p < 49) {
#pragma unroll
        for (int r = 0; r < 4; ++r) sm.c3.ct[wave * 16 + lg * 4 + r][p] = acc[j][r];
      }
    }
    __syncthreads();

    const size_t obase = (size_t)b * 50176;
    for (int i = tid; i < 64 * 49; i += 256) {
      int cl = i / 49;
      int q = i - cl * 49;
      int qy = q / 7, qx = q - qy * 7;
      int rm = qy > 0 ? qy - 1 : 0, rp = qy < 6 ? qy + 1 : 6;
      float* dst = o_aux3 + obase + (size_t)(o0 + cl) * 196 + (size_t)(2 * qy) * 14 + 2 * qx;
      up_quad_rows(&sm.c3.ct[cl][rm * 7], &sm.c3.ct[cl][qy * 7], &sm.c3.ct[cl][rp * 7],
                   qx, 7, dst, 14);
    }
  } else {
    // ============ output copies (no setup dependency) ============
    int idx = (raw - 1920) * 256 + tid;
    const int stride = 64 * 256;
    float4* o4 = (float4*)out;
    const size_t W1 = 6029312;  // o_w1 offset in float4s
    for (int i = idx; i < 8192; i += stride) o4[i] = ((const float4*)xf)[i];
    for (int i = idx; i < 50176; i += stride) o4[W1 + i] = ((const float4*)w1)[i];
    for (int i = idx; i < 25088; i += stride) o4[W1 + 50176 + i] = ((const float4*)w2)[i];
    for (int i = idx; i < 12544; i += stride) o4[W1 + 75264 + i] = ((const float4*)w3)[i];
    for (int i = idx; i < 6272; i += stride) o4[W1 + 87808 + i] = ((const float4*)w4s)[i];
  }
}

extern "C" void kernel_launch(void* const* d_in, const int* in_sizes, int n_in,
                              void* d_out, int out_size, void* d_ws, size_t ws_size,
                              hipStream_t stream) {
  const float* f1      = (const float*)d_in[0];
  const float* f2      = (const float*)d_in[1];
  const float* f3      = (const float*)d_in[2];
  const float* f4      = (const float*)d_in[3];
  const float* x_final = (const float*)d_in[4];
  const float* cw1     = (const float*)d_in[5];
  const float* cb1     = (const float*)d_in[6];
  const float* cw2     = (const float*)d_in[7];
  const float* cb2     = (const float*)d_in[8];
  const float* cw3     = (const float*)d_in[9];
  const float* cb3     = (const float*)d_in[10];
  const float* cw4     = (const float*)d_in[11];
  const float* cb4     = (const float*)d_in[12];
  const float* w1      = (const float*)d_in[13];
  const float* w2      = (const float*)d_in[14];
  const float* w3      = (const float*)d_in[15];
  const float* w4      = (const float*)d_in[16];
  const int*   perms   = (const int*)d_in[17];

  float* out = (float*)d_out;

  unsigned short* ws  = (unsigned short*)d_ws;
  unsigned short* inT = ws;                      // 64*64*512      = 2,097,152
  unsigned short* f1T = inT + 2097152;           // 64*784*64      = 3,211,264
  unsigned short* f2T = f1T + 3211264;           // 64*196*128     = 1,605,632
  unsigned short* f3T = f2T + 1605632;           // 64*64*128      =   524,288
  unsigned short* w4b = f3T + 524288;            // 512*512        =   262,144
  unsigned short* w1b = w4b + 262144;            // 64*64          =     4,096
  unsigned short* w2b = w1b + 4096;              // 128*128        =    16,384
  unsigned short* w3b = w2b + 16384;             // 256*128        =    32,768

  setup256<<<1408, 256, 0, stream>>>(f1, f2, f3, f4, cw1, cw2, cw3, cw4,
                                     f1T, f2T, f3T, inT, w1b, w2b, w3b, w4b);
  fused_all<<<1984, 256, 0, stream>>>(f1T, f2T, f3T, inT, w1b, w2b, w3b, w4b,
                                      cb1, cb2, cb3, cb4,
                                      x_final, w1, w2, w3, w4, perms, out);
}

// Round 21
// 46.770 us; speedup vs baseline: 1.5662x; 1.0027x over previous
//
#include <hip/hip_runtime.h>
#include <hip/hip_bf16.h>
#include <cstddef>

typedef __attribute__((ext_vector_type(8))) short bf16x8;
typedef __attribute__((ext_vector_type(4))) float f32x4;

__device__ __forceinline__ float4 ld4(const float* p) { return *(const float4*)p; }
__device__ __forceinline__ unsigned short f2bf(float v) {
  __hip_bfloat16 h = __float2bfloat16(v);
  return *(unsigned short*)&h;
}

// 2x bilinear upsample of one 2x2 quad (three halo-resolved source rows).
__device__ __forceinline__ void up_quad_rows(const float* __restrict__ s0,
                                             const float* __restrict__ s1,
                                             const float* __restrict__ s2,
                                             int qx, int W, float* __restrict__ dst, int pitch) {
  int cm = qx > 0 ? qx - 1 : 0, cp = qx < W - 1 ? qx + 1 : W - 1;
  float tA0 = 0.25f * s0[cm] + 0.75f * s0[qx], tA1 = 0.75f * s0[qx] + 0.25f * s0[cp];
  float tB0 = 0.25f * s1[cm] + 0.75f * s1[qx], tB1 = 0.75f * s1[qx] + 0.25f * s1[cp];
  float tC0 = 0.25f * s2[cm] + 0.75f * s2[qx], tC1 = 0.75f * s2[qx] + 0.25f * s2[cp];
  *(float2*)dst = make_float2(0.25f * tA0 + 0.75f * tB0, 0.25f * tA1 + 0.75f * tB1);
  *(float2*)(dst + pitch) = make_float2(0.75f * tB0 + 0.25f * tC0, 0.75f * tB1 + 0.25f * tC1);
}

// 2x upsample of TWO adjacent quads (qx0 even): 4-wide x 2-row patch, float4 stores.
__device__ __forceinline__ void up_quad2(const float* __restrict__ s0,
                                         const float* __restrict__ s1,
                                         const float* __restrict__ s2,
                                         int qx0, int W, float* __restrict__ dst, int pitch) {
  int cm = qx0 > 0 ? qx0 - 1 : 0;
  int c2 = qx0 + 2 < W ? qx0 + 2 : W - 1;
  float Am = s0[cm], A0 = s0[qx0], A1 = s0[qx0 + 1], A2 = s0[c2];
  float Bm = s1[cm], B0 = s1[qx0], B1 = s1[qx0 + 1], B2 = s1[c2];
  float Cm = s2[cm], C0 = s2[qx0], C1 = s2[qx0 + 1], C2 = s2[c2];
  float hA0 = 0.25f * Am + 0.75f * A0, hA1 = 0.75f * A0 + 0.25f * A1;
  float hA2 = 0.25f * A0 + 0.75f * A1, hA3 = 0.75f * A1 + 0.25f * A2;
  float hB0 = 0.25f * Bm + 0.75f * B0, hB1 = 0.75f * B0 + 0.25f * B1;
  float hB2 = 0.25f * B0 + 0.75f * B1, hB3 = 0.75f * B1 + 0.25f * B2;
  float hC0 = 0.25f * Cm + 0.75f * C0, hC1 = 0.75f * C0 + 0.25f * C1;
  float hC2 = 0.25f * C0 + 0.75f * C1, hC3 = 0.75f * C1 + 0.25f * C2;
  *(float4*)dst = make_float4(0.25f * hA0 + 0.75f * hB0, 0.25f * hA1 + 0.75f * hB1,
                              0.25f * hA2 + 0.75f * hB2, 0.25f * hA3 + 0.75f * hB3);
  *(float4*)(dst + pitch) = make_float4(0.75f * hB0 + 0.25f * hC0, 0.75f * hB1 + 0.25f * hC1,
                                        0.75f * hB2 + 0.25f * hC2, 0.75f * hB3 + 0.25f * hC3);
}

// ---------------------------------------------------------------------------
// setup256 (R20 verbatim): fine-grained transposes + weight conversions.
// ---------------------------------------------------------------------------
__global__ void __launch_bounds__(256)
setup256(const float* __restrict__ f1, const float* __restrict__ f2,
         const float* __restrict__ f3, const float* __restrict__ f4,
         const float* __restrict__ cw1, const float* __restrict__ cw2,
         const float* __restrict__ cw3, const float* __restrict__ cw4,
         unsigned short* __restrict__ f1T, unsigned short* __restrict__ f2T,
         unsigned short* __restrict__ f3T, unsigned short* __restrict__ inT,
         unsigned short* __restrict__ w1b, unsigned short* __restrict__ w2b,
         unsigned short* __restrict__ w3b, unsigned short* __restrict__ w4b) {
  __shared__ unsigned short stile[12800];
  const int bid = blockIdx.x, tid = threadIdx.x;

  if (bid < 512) {
    const int b = bid >> 3, c0 = (bid & 7) * 64;
    const float* src = f4 + ((size_t)b * 512 + c0) * 49;
    for (int i = tid; i < 64 * 49; i += 256) {
      int ci = i / 49, p = i - ci * 49;
      stile[ci * 50 + p] = f2bf(src[i]);
    }
    __syncthreads();
    unsigned short* dst = inT + (size_t)b * 32768 + c0;
    for (int i = tid; i < 64 * 64; i += 256) {
      int p = i >> 6, ci = i & 63;
      dst[(size_t)p * 512 + ci] = (p < 49) ? stile[ci * 50 + p] : (unsigned short)0;
    }
  } else if (bid < 1024) {
    const int t = bid - 512, b = t >> 3, q = t & 7;
    const float* src = f1 + (size_t)b * 50176 + q * 98;
    for (int i = tid; i < 64 * 98; i += 256) {
      int ci = i / 98, px = i - ci * 98;
      stile[ci * 98 + px] = f2bf(src[(size_t)ci * 784 + px]);
    }
    __syncthreads();
    unsigned short* dst = f1T + ((size_t)b * 784 + q * 98) * 64;
    for (int i = tid; i < 98 * 8; i += 256) {
      int p = i >> 3, cg = (i & 7) * 8;
      unsigned short tmp[8];
#pragma unroll
      for (int k = 0; k < 8; ++k) tmp[k] = stile[(cg + k) * 98 + p];
      *(ushort4*)(dst + (size_t)p * 64 + cg) = *(ushort4*)tmp;
      *(ushort4*)(dst + (size_t)p * 64 + cg + 4) = *(ushort4*)(tmp + 4);
    }
  } else if (bid < 1280) {
    const int t = bid - 1024, b = t >> 2, q = t & 3;
    const float* src = f2 + (size_t)b * 25088 + q * 49;
    for (int i = tid; i < 128 * 49; i += 256) {
      int ci = i / 49, px = i - ci * 49;
      stile[ci * 49 + px] = f2bf(src[(size_t)ci * 196 + px]);
    }
    __syncthreads();
    unsigned short* dst = f2T + ((size_t)b * 196 + q * 49) * 128;
    for (int i = tid; i < 49 * 16; i += 256) {
      int p = i >> 4, cg = (i & 15) * 8;
      unsigned short tmp[8];
#pragma unroll
      for (int k = 0; k < 8; ++k) tmp[k] = stile[(cg + k) * 49 + p];
      *(ushort4*)(dst + (size_t)p * 128 + cg) = *(ushort4*)tmp;
      *(ushort4*)(dst + (size_t)p * 128 + cg + 4) = *(ushort4*)(tmp + 4);
    }
  } else if (bid < 1344) {
    const int b = bid - 1280;
    const float* src = f3 + (size_t)b * 6272;
    for (int i = tid; i < 128 * 49; i += 256) {
      int ci = i / 49, px = i - ci * 49;
      stile[ci * 49 + px] = f2bf(src[i]);
    }
    __syncthreads();
    unsigned short* dst = f3T + (size_t)b * 8192;
    for (int i = tid; i < 64 * 16; i += 256) {
      int p = i >> 4, cg = (i & 15) * 8;
      unsigned short tmp[8];
#pragma unroll
      for (int k = 0; k < 8; ++k) tmp[k] = (p < 49) ? stile[(cg + k) * 49 + p] : (unsigned short)0;
      *(ushort4*)(dst + (size_t)p * 128 + cg) = *(ushort4*)tmp;
      *(ushort4*)(dst + (size_t)p * 128 + cg + 4) = *(ushort4*)(tmp + 4);
    }
  } else {
    int idx = (bid - 1344) * 256 + tid;
    const int stride = 64 * 256;
#define CVT(DST, SRC, N)                                          \
    for (int i = idx; i < (N); i += stride) {                     \
      float4 v = ld4((SRC) + 4 * i);                              \
      ushort4 u;                                                  \
      u.x = f2bf(v.x); u.y = f2bf(v.y); u.z = f2bf(v.z); u.w = f2bf(v.w); \
      *(ushort4*)((DST) + 4 * i) = u;                             \
    }
    CVT(w4b, cw4, 65536)
    CVT(w1b, cw1, 1024)
    CVT(w2b, cw2, 4096)
    CVT(w3b, cw3, 8192)
#undef CVT
  }
}

// Odd row strides (253/127) to spread LDS banks; scalar accesses only.
struct P1M { float ct[16][253]; int inv[4][16]; };
struct C2M { float ct[32][127]; };
struct C3M { float ct[64][49]; };
union SmemM { P1M p1; C2M c2; C3M c3; };

// Balanced XCD-local decode (R13-proven).
__device__ __forceinline__ int2 xcd_decode(int d, int wpb_log) {
  int xcd = d & 7;
  int i = (d >> 3) & ((1 << wpb_log) - 1);
  int b = (((d >> (3 + wpb_log)) << 3) | xcd);
  return make_int2(b, i);
}

// ---------------------------------------------------------------------------
// fused_all: 1984 blocks x 256 thr (R20 conv bodies; division-free epilogues).
//  [0,128)     conv4 | [128,1152) perm1 | [1152,1664) conv2
//  [1664,1920) conv3 | [1920,1984) output copies
// ---------------------------------------------------------------------------
__global__ void __launch_bounds__(256)
fused_all(const unsigned short* __restrict__ f1T, const unsigned short* __restrict__ f2T,
          const unsigned short* __restrict__ f3T, const unsigned short* __restrict__ inT,
          const unsigned short* __restrict__ w1b, const unsigned short* __restrict__ w2b,
          const unsigned short* __restrict__ w3b, const unsigned short* __restrict__ w4b,
          const float* __restrict__ cb1, const float* __restrict__ cb2,
          const float* __restrict__ cb3, const float* __restrict__ cb4,
          const float* __restrict__ xf, const float* __restrict__ w1,
          const float* __restrict__ w2, const float* __restrict__ w3,
          const float* __restrict__ w4s, const int* __restrict__ perms,
          float* __restrict__ out) {
  __shared__ SmemM sm;
  const int raw = blockIdx.x, tid = threadIdx.x;
  const int wave = tid >> 6, lane = tid & 63;
  const int l15 = lane & 15, lg = lane >> 4;
  float* o_aux1 = out + 32768;
  float* o_aux2 = o_aux1 + 12845056;
  float* o_aux3 = o_aux2 + 6422528;
  float* o_aux4 = o_aux3 + 3211264;

  if (raw < 128) {
    // ============ conv4: wave = 64 och (M=4), packed operands ============
    int2 bi = xcd_decode(raw, 1);
    const int b = bi.x;
    const int ob = bi.y * 256 + wave * 64;

    f32x4 acc[4][4];
#pragma unroll
    for (int mi = 0; mi < 4; ++mi) {
      float bv0 = cb4[ob + mi * 16 + lg * 4 + 0], bv1 = cb4[ob + mi * 16 + lg * 4 + 1];
      float bv2 = cb4[ob + mi * 16 + lg * 4 + 2], bv3 = cb4[ob + mi * 16 + lg * 4 + 3];
#pragma unroll
      for (int n = 0; n < 4; ++n) {
        acc[mi][n][0] = bv0; acc[mi][n][1] = bv1; acc[mi][n][2] = bv2; acc[mi][n][3] = bv3;
      }
    }
    const unsigned short* bp = inT + (size_t)b * 32768 + (size_t)l15 * 512 + lg * 8;
#pragma unroll 2
    for (int k0 = 0; k0 < 512; k0 += 32) {
      bf16x8 A0 = *(const bf16x8*)(w4b + (size_t)(ob + 0 + l15) * 512 + k0 + lg * 8);
      bf16x8 A1 = *(const bf16x8*)(w4b + (size_t)(ob + 16 + l15) * 512 + k0 + lg * 8);
      bf16x8 A2 = *(const bf16x8*)(w4b + (size_t)(ob + 32 + l15) * 512 + k0 + lg * 8);
      bf16x8 A3 = *(const bf16x8*)(w4b + (size_t)(ob + 48 + l15) * 512 + k0 + lg * 8);
      bf16x8 B0 = *(const bf16x8*)(bp + k0);
      bf16x8 B1 = *(const bf16x8*)(bp + 16 * 512 + k0);
      bf16x8 B2 = *(const bf16x8*)(bp + 32 * 512 + k0);
      bf16x8 B3 = *(const bf16x8*)(bp + 48 * 512 + k0);
      acc[0][0] = __builtin_amdgcn_mfma_f32_16x16x32_bf16(A0, B0, acc[0][0], 0, 0, 0);
      acc[0][1] = __builtin_amdgcn_mfma_f32_16x16x32_bf16(A0, B1, acc[0][1], 0, 0, 0);
      acc[0][2] = __builtin_amdgcn_mfma_f32_16x16x32_bf16(A0, B2, acc[0][2], 0, 0, 0);
      acc[0][3] = __builtin_amdgcn_mfma_f32_16x16x32_bf16(A0, B3, acc[0][3], 0, 0, 0);
      acc[1][0] = __builtin_amdgcn_mfma_f32_16x16x32_bf16(A1, B0, acc[1][0], 0, 0, 0);
      acc[1][1] = __builtin_amdgcn_mfma_f32_16x16x32_bf16(A1, B1, acc[1][1], 0, 0, 0);
      acc[1][2] = __builtin_amdgcn_mfma_f32_16x16x32_bf16(A1, B2, acc[1][2], 0, 0, 0);
      acc[1][3] = __builtin_amdgcn_mfma_f32_16x16x32_bf16(A1, B3, acc[1][3], 0, 0, 0);
      acc[2][0] = __builtin_amdgcn_mfma_f32_16x16x32_bf16(A2, B0, acc[2][0], 0, 0, 0);
      acc[2][1] = __builtin_amdgcn_mfma_f32_16x16x32_bf16(A2, B1, acc[2][1], 0, 0, 0);
      acc[2][2] = __builtin_amdgcn_mfma_f32_16x16x32_bf16(A2, B2, acc[2][2], 0, 0, 0);
      acc[2][3] = __builtin_amdgcn_mfma_f32_16x16x32_bf16(A2, B3, acc[2][3], 0, 0, 0);
      acc[3][0] = __builtin_amdgcn_mfma_f32_16x16x32_bf16(A3, B0, acc[3][0], 0, 0, 0);
      acc[3][1] = __builtin_amdgcn_mfma_f32_16x16x32_bf16(A3, B1, acc[3][1], 0, 0, 0);
      acc[3][2] = __builtin_amdgcn_mfma_f32_16x16x32_bf16(A3, B2, acc[3][2], 0, 0, 0);
      acc[3][3] = __builtin_amdgcn_mfma_f32_16x16x32_bf16(A3, B3, acc[3][3], 0, 0, 0);
    }
    float* outb = o_aux4 + (size_t)b * 25088;
#pragma unroll
    for (int mi = 0; mi < 4; ++mi) {
#pragma unroll
      for (int n = 0; n < 4; ++n) {
        int p = n * 16 + l15;
        if (p < 49) {
#pragma unroll
          for (int r = 0; r < 4; ++r) {
            int o = ob + mi * 16 + lg * 4 + r;
            outb[(size_t)o * 49 + p] = acc[mi][n][r];
          }
        }
      }
    }
  } else if (raw < 1152) {
    // ============ perm1: 16 och x 7-row chunk ============
    int2 bi = xcd_decode(raw - 128, 4);
    const int b = bi.x;
    const int o0 = (bi.y >> 2) * 16;
    const int r0 = (bi.y & 3) * 7, base = r0 - 1;

    if (tid >= 128 && tid < 192) {
      int t2 = tid - 128;
      int i = t2 >> 4, cl = t2 & 15;
      int c = o0 + cl;
      int r = 0;
      for (int j = 0; j < 64; ++j)
        if (perms[i * 64 + j] == c) r = j;
      sm.p1.inv[i][cl] = r;
    }

    const unsigned short* bp[4];
#pragma unroll
    for (int j = 0; j < 4; ++j) {
      int praw = wave * 64 + j * 16 + l15;
      int p = praw < 251 ? praw : 251;
      int lr = p / 28, x = p - lr * 28;
      int sr = base + lr;
      sr = sr < 0 ? 0 : (sr > 27 ? 27 : sr);
      bp[j] = f1T + ((size_t)b * 784 + sr * 28 + x) * 64 + lg * 8;
    }
    f32x4 acc[4];
    {
      float bv0 = cb1[o0 + lg * 4 + 0], bv1 = cb1[o0 + lg * 4 + 1];
      float bv2 = cb1[o0 + lg * 4 + 2], bv3 = cb1[o0 + lg * 4 + 3];
#pragma unroll
      for (int j = 0; j < 4; ++j) {
        acc[j][0] = bv0; acc[j][1] = bv1; acc[j][2] = bv2; acc[j][3] = bv3;
      }
    }
    const unsigned short* ap = w1b + (size_t)(o0 + l15) * 64 + lg * 8;
#pragma unroll
    for (int ks = 0; ks < 2; ++ks) {
      bf16x8 A = *(const bf16x8*)(ap + ks * 32);
#pragma unroll
      for (int j = 0; j < 4; ++j) {
        bf16x8 B = *(const bf16x8*)(bp[j] + ks * 32);
        acc[j] = __builtin_amdgcn_mfma_f32_16x16x32_bf16(A, B, acc[j], 0, 0, 0);
      }
    }
#pragma unroll
    for (int j = 0; j < 4; ++j) {
      int praw = wave * 64 + j * 16 + l15;
      if (praw < 252) {
#pragma unroll
        for (int r = 0; r < 4; ++r) sm.p1.ct[lg * 4 + r][praw] = acc[j][r];
      }
    }
    __syncthreads();

    // division-free epilogue: cl = tid>>4, pr = tid&15 (<14); ly loop 0..6.
    // quadrant row bit is block-constant (qy>=14 <=> r0>=14).
    {
      const int cl = tid >> 4, pr = tid & 15;
      if (pr < 14) {
        const int qx0 = 2 * pr;
        const int qi = ((r0 >= 14) ? 2 : 0) + ((qx0 >= 14) ? 1 : 0);
        const int j = sm.p1.inv[qi][cl];
        float* dstc = o_aux1 + (size_t)b * 200704 + (size_t)j * 3136 + 2 * qx0;
#pragma unroll
        for (int ly = 0; ly < 7; ++ly) {
          int qy = r0 + ly;
          int lr = ly + 1;
          up_quad2(&sm.p1.ct[cl][(lr - 1) * 28], &sm.p1.ct[cl][lr * 28],
                   &sm.p1.ct[cl][(lr + 1) * 28], qx0, 28,
                   dstc + (size_t)(2 * qy) * 56, 56);
        }
      }
    }
  } else if (raw < 1664) {
    // ============ conv2: 32 och x 7-row chunk ============
    int2 bi = xcd_decode(raw - 1152, 3);
    const int b = bi.x;
    const int o0 = (bi.y >> 1) * 32;
    const int r0 = (bi.y & 1) * 7, base = r0 - 1;
    const int og = wave >> 1, nt = wave & 1;
    const int om = o0 + og * 16;

    const unsigned short* bp[4];
#pragma unroll
    for (int j = 0; j < 4; ++j) {
      int praw = nt * 64 + j * 16 + l15;
      int p = praw < 125 ? praw : 125;
      int lr = p / 14, x = p - lr * 14;
      int sr = base + lr;
      sr = sr < 0 ? 0 : (sr > 13 ? 13 : sr);
      bp[j] = f2T + ((size_t)b * 196 + sr * 14 + x) * 128 + lg * 8;
    }
    f32x4 acc[4];
    {
      float bv0 = cb2[om + lg * 4 + 0], bv1 = cb2[om + lg * 4 + 1];
      float bv2 = cb2[om + lg * 4 + 2], bv3 = cb2[om + lg * 4 + 3];
#pragma unroll
      for (int j = 0; j < 4; ++j) {
        acc[j][0] = bv0; acc[j][1] = bv1; acc[j][2] = bv2; acc[j][3] = bv3;
      }
    }
    const unsigned short* ap = w2b + (size_t)(om + l15) * 128 + lg * 8;
#pragma unroll
    for (int ks = 0; ks < 4; ++ks) {
      bf16x8 A = *(const bf16x8*)(ap + ks * 32);
#pragma unroll
      for (int j = 0; j < 4; ++j) {
        bf16x8 B = *(const bf16x8*)(bp[j] + ks * 32);
        acc[j] = __builtin_amdgcn_mfma_f32_16x16x32_bf16(A, B, acc[j], 0, 0, 0);
      }
    }
#pragma unroll
    for (int j = 0; j < 4; ++j) {
      int praw = nt * 64 + j * 16 + l15;
      if (praw < 126) {
#pragma unroll
        for (int r = 0; r < 4; ++r) sm.c2.ct[og * 16 + lg * 4 + r][praw] = acc[j][r];
      }
    }
    __syncthreads();

    // division-free epilogue: cl = tid>>3 (0..31), pr = tid&7 (<7); ly 0..6.
    {
      const int cl = tid >> 3, pr = tid & 7;
      if (pr < 7) {
        const int qx0 = 2 * pr;
        float* dstc = o_aux2 + (size_t)b * 100352 + (size_t)(o0 + cl) * 784 + 2 * qx0;
#pragma unroll
        for (int ly = 0; ly < 7; ++ly) {
          int qy = r0 + ly;
          int lr = ly + 1;
          up_quad2(&sm.c2.ct[cl][(lr - 1) * 14], &sm.c2.ct[cl][lr * 14],
                   &sm.c2.ct[cl][(lr + 1) * 14], qx0, 14,
                   dstc + (size_t)(2 * qy) * 28, 28);
        }
      }
    }
  } else if (raw < 1920) {
    // ============ conv3: 64 och ============
    int2 bi = xcd_decode(raw - 1664, 2);
    const int b = bi.x;
    const int o0 = bi.y * 64;
    const int om = o0 + wave * 16;

    const unsigned short* bp[4];
#pragma unroll
    for (int j = 0; j < 4; ++j) {
      int p = j * 16 + l15;  // f3T zero-padded to 64 rows
      bp[j] = f3T + ((size_t)b * 64 + p) * 128 + lg * 8;
    }
    f32x4 acc[4];
    {
      float bv0 = cb3[om + lg * 4 + 0], bv1 = cb3[om + lg * 4 + 1];
      float bv2 = cb3[om + lg * 4 + 2], bv3 = cb3[om + lg * 4 + 3];
#pragma unroll
      for (int j = 0; j < 4; ++j) {
        acc[j][0] = bv0; acc[j][1] = bv1; acc[j][2] = bv2; acc[j][3] = bv3;
      }
    }
    const unsigned short* ap = w3b + (size_t)(om + l15) * 128 + lg * 8;
#pragma unroll
    for (int ks = 0; ks < 4; ++ks) {
      bf16x8 A = *(const bf16x8*)(ap + ks * 32);
#pragma unroll
      for (int j = 0; j < 4; ++j) {
        bf16x8 B = *(const bf16x8*)(bp[j] + ks * 32);
        acc[j] = __builtin_amdgcn_mfma_f32_16x16x32_bf16(A, B, acc[j], 0, 0, 0);
      }
    }
#pragma unroll
    for (int j = 0; j < 4; ++j) {
      int p = j * 16 + l15;
      if (p < 49) {
#pragma unroll
        for (int r = 0; r < 4; ++r) sm.c3.ct[wave * 16 + lg * 4 + r][p] = acc[j][r];
      }
    }
    __syncthreads();

    // division-free epilogue: qx = tid&7 (<7), c32 = tid>>3; 2 ch-halves x 7 rows.
    {
      const int qx = tid & 7, c32 = tid >> 3;
      if (qx < 7) {
        const size_t obase = (size_t)b * 50176;
#pragma unroll
        for (int h = 0; h < 2; ++h) {
          const int cl = c32 + h * 32;
          float* dstc = o_aux3 + obase + (size_t)(o0 + cl) * 196 + 2 * qx;
#pragma unroll
          for (int qy = 0; qy < 7; ++qy) {
            int rm = qy > 0 ? qy - 1 : 0, rp = qy < 6 ? qy + 1 : 6;
            up_quad_rows(&sm.c3.ct[cl][rm * 7], &sm.c3.ct[cl][qy * 7],
                         &sm.c3.ct[cl][rp * 7], qx, 7,
                         dstc + (size_t)(2 * qy) * 14, 14);
          }
        }
      }
    }
  } else {
    // ============ output copies (no setup dependency) ============
    int idx = (raw - 1920) * 256 + tid;
    const int stride = 64 * 256;
    float4* o4 = (float4*)out;
    const size_t W1 = 6029312;  // o_w1 offset in float4s
    for (int i = idx; i < 8192; i += stride) o4[i] = ((const float4*)xf)[i];
    for (int i = idx; i < 50176; i += stride) o4[W1 + i] = ((const float4*)w1)[i];
    for (int i = idx; i < 25088; i += stride) o4[W1 + 50176 + i] = ((const float4*)w2)[i];
    for (int i = idx; i < 12544; i += stride) o4[W1 + 75264 + i] = ((const float4*)w3)[i];
    for (int i = idx; i < 6272; i += stride) o4[W1 + 87808 + i] = ((const float4*)w4s)[i];
  }
}

extern "C" void kernel_launch(void* const* d_in, const int* in_sizes, int n_in,
                              void* d_out, int out_size, void* d_ws, size_t ws_size,
                              hipStream_t stream) {
  const float* f1      = (const float*)d_in[0];
  const float* f2      = (const float*)d_in[1];
  const float* f3      = (const float*)d_in[2];
  const float* f4      = (const float*)d_in[3];
  const float* x_final = (const float*)d_in[4];
  const float* cw1     = (const float*)d_in[5];
  const float* cb1     = (const float*)d_in[6];
  const float* cw2     = (const float*)d_in[7];
  const float* cb2     = (const float*)d_in[8];
  const float* cw3     = (const float*)d_in[9];
  const float* cb3     = (const float*)d_in[10];
  const float* cw4     = (const float*)d_in[11];
  const float* cb4     = (const float*)d_in[12];
  const float* w1      = (const float*)d_in[13];
  const float* w2      = (const float*)d_in[14];
  const float* w3      = (const float*)d_in[15];
  const float* w4      = (const float*)d_in[16];
  const int*   perms   = (const int*)d_in[17];

  float* out = (float*)d_out;

  unsigned short* ws  = (unsigned short*)d_ws;
  unsigned short* inT = ws;                      // 64*64*512      = 2,097,152
  unsigned short* f1T = inT + 2097152;           // 64*784*64      = 3,211,264
  unsigned short* f2T = f1T + 3211264;           // 64*196*128     = 1,605,632
  unsigned short* f3T = f2T + 1605632;           // 64*64*128      =   524,288
  unsigned short* w4b = f3T + 524288;            // 512*512        =   262,144
  unsigned short* w1b = w4b + 262144;            // 64*64          =     4,096
  unsigned short* w2b = w1b + 4096;              // 128*128        =    16,384
  unsigned short* w3b = w2b + 16384;             // 256*128        =    32,768

  setup256<<<1408, 256, 0, stream>>>(f1, f2, f3, f4, cw1, cw2, cw3, cw4,
                                     f1T, f2T, f3T, inT, w1b, w2b, w3b, w4b);
  fused_all<<<1984, 256, 0, stream>>>(f1T, f2T, f3T, inT, w1b, w2b, w3b, w4b,
                                      cb1, cb2, cb3, cb4,
                                      x_final, w1, w2, w3, w4, perms, out);
}